// Round 2
// baseline (5021.585 us; speedup 1.0000x reference)
//
#include <hip/hip_runtime.h>
#include <math.h>

#define BB 4
#define SS 2048
#define DD 1024
#define HH 16
#define DHH 64
#define DFF 4096
static constexpr float LN_EPS = 1e-5f;

// ---------------------------------------------------------------------------
// Repack Wqkv [H, D, 3*DH] -> Wq2 [D, H*3*DH] so QKV is a standard GEMM.
// ---------------------------------------------------------------------------
__global__ __launch_bounds__(256) void repack_wqkv_kernel(
    const float* __restrict__ Wqkv, float* __restrict__ Wq2) {
    int idx = blockIdx.x * 256 + threadIdx.x;           // D*3072 total
    if (idx >= DD * HH * 3 * DHH) return;
    int d = idx / (HH * 3 * DHH);
    int c = idx % (HH * 3 * DHH);
    int h = c / (3 * DHH);
    int e = c % (3 * DHH);
    Wq2[idx] = Wqkv[((size_t)h * DD + d) * (3 * DHH) + e];
}

// ---------------------------------------------------------------------------
// Generic fp32 GEMM: C[M,N] = A[M,K] @ Bm[K,N] (+epilogue)
// MODE 0: plain   MODE 1: +bias   MODE 2: +bias, exact GELU   MODE 3: +bias+residual
// M,N multiples of 64; K multiple of 16.
// ---------------------------------------------------------------------------
template <int MODE>
__global__ __launch_bounds__(256) void gemm_kernel(
    const float* __restrict__ A, const float* __restrict__ Bm,
    float* __restrict__ C, const float* __restrict__ bias,
    const float* __restrict__ resid, int M, int N, int K) {
    __shared__ float As[16][64];   // [k][m]
    __shared__ float Bs[16][64];   // [k][n]

    const int tx = threadIdx.x % 16;   // col group
    const int ty = threadIdx.x / 16;   // row group
    const int row0 = blockIdx.y * 64;
    const int col0 = blockIdx.x * 64;

    float acc[4][4];
#pragma unroll
    for (int i = 0; i < 4; ++i)
#pragma unroll
        for (int j = 0; j < 4; ++j) acc[i][j] = 0.f;

    const int ar = threadIdx.x / 4;           // 0..63 row within tile
    const int ak = (threadIdx.x % 4) * 4;     // 0..12 k within tile
    const int br = threadIdx.x / 16;          // 0..15 k row
    const int bc = (threadIdx.x % 16) * 4;    // 0..60 col

    for (int k0 = 0; k0 < K; k0 += 16) {
        float4 a4 = *(const float4*)&A[(size_t)(row0 + ar) * K + k0 + ak];
        As[ak + 0][ar] = a4.x;
        As[ak + 1][ar] = a4.y;
        As[ak + 2][ar] = a4.z;
        As[ak + 3][ar] = a4.w;
        *(float4*)&Bs[br][bc] =
            *(const float4*)&Bm[(size_t)(k0 + br) * N + col0 + bc];
        __syncthreads();
#pragma unroll
        for (int kk = 0; kk < 16; ++kk) {
            float a[4], b[4];
            *(float4*)a = *(const float4*)&As[kk][ty * 4];
            *(float4*)b = *(const float4*)&Bs[kk][tx * 4];
#pragma unroll
            for (int i = 0; i < 4; ++i)
#pragma unroll
                for (int j = 0; j < 4; ++j) acc[i][j] += a[i] * b[j];
        }
        __syncthreads();
    }

#pragma unroll
    for (int i = 0; i < 4; ++i) {
        const int r = row0 + ty * 4 + i;
#pragma unroll
        for (int j = 0; j < 4; ++j) {
            const int c = col0 + tx * 4 + j;
            float v = acc[i][j];
            if (MODE >= 1) v += bias[c];
            if (MODE == 2) v = 0.5f * v * (1.0f + erff(v * 0.70710678118654752f));
            if (MODE == 3) v += resid[(size_t)r * N + c];
            C[(size_t)r * N + c] = v;
        }
    }
}

// ---------------------------------------------------------------------------
// Causal attention. qkv layout: [B*S, H*3*DH], per token per head: q|k|v (64 each).
// One thread per query row; online softmax; K/V loads are wave-uniform.
// Output att [B*S, D] with head-concat layout.
// ---------------------------------------------------------------------------
__global__ __launch_bounds__(256) void attn_kernel(
    const float* __restrict__ qkv, float* __restrict__ att) {
    const int bh = blockIdx.y;
    const int b = bh / HH;
    const int h = bh % HH;
    const int qi = blockIdx.x * 256 + threadIdx.x;
    const size_t rs = HH * 3 * DHH;  // 3072 row stride

    const float* qp = qkv + ((size_t)b * SS + qi) * rs + (size_t)h * (3 * DHH);
    float qreg[DHH];
#pragma unroll
    for (int j = 0; j < 16; ++j) {
        float4 t4 = ((const float4*)qp)[j];
        qreg[4 * j + 0] = t4.x; qreg[4 * j + 1] = t4.y;
        qreg[4 * j + 2] = t4.z; qreg[4 * j + 3] = t4.w;
    }
    float o[DHH];
#pragma unroll
    for (int j = 0; j < DHH; ++j) o[j] = 0.f;

    float m = -INFINITY, l = 0.f;
    const float scale = 0.125f;  // 1/sqrt(64)

    const float* kbase = qkv + ((size_t)b * SS) * rs + (size_t)h * (3 * DHH) + DHH;
    const float* vbase = kbase + DHH;

    for (int t = 0; t <= qi; ++t) {
        const float4* kp = (const float4*)(kbase + (size_t)t * rs);
        float s = 0.f;
#pragma unroll
        for (int j = 0; j < 16; ++j) {
            float4 kk = kp[j];
            s += kk.x * qreg[4 * j + 0] + kk.y * qreg[4 * j + 1] +
                 kk.z * qreg[4 * j + 2] + kk.w * qreg[4 * j + 3];
        }
        s *= scale;
        float mn = fmaxf(m, s);
        float corr = __expf(m - mn);   // 0 on first iter (m=-inf)
        float p = __expf(s - mn);
        l = l * corr + p;
        const float4* vp = (const float4*)(vbase + (size_t)t * rs);
#pragma unroll
        for (int j = 0; j < 16; ++j) {
            float4 vv = vp[j];
            o[4 * j + 0] = o[4 * j + 0] * corr + p * vv.x;
            o[4 * j + 1] = o[4 * j + 1] * corr + p * vv.y;
            o[4 * j + 2] = o[4 * j + 2] * corr + p * vv.z;
            o[4 * j + 3] = o[4 * j + 3] * corr + p * vv.w;
        }
        m = mn;
    }
    const float inv = 1.f / l;
    float* op = att + ((size_t)b * SS + qi) * DD + (size_t)h * DHH;
#pragma unroll
    for (int j = 0; j < 16; ++j) {
        float4 r4;
        r4.x = o[4 * j + 0] * inv; r4.y = o[4 * j + 1] * inv;
        r4.z = o[4 * j + 2] * inv; r4.w = o[4 * j + 3] * inv;
        ((float4*)op)[j] = r4;
    }
}

// ---------------------------------------------------------------------------
// Row LayerNorm over D=1024. One block (256 threads) per row. Two-pass
// (mean, then mean of squared deviation) matching the reference. Safe
// in-place (X == Y): each block reads its whole row into registers first.
// ---------------------------------------------------------------------------
__global__ __launch_bounds__(256) void ln_kernel(
    const float* __restrict__ X, const float* __restrict__ g,
    const float* __restrict__ bta, float* __restrict__ Y) {
    const int row = blockIdx.x;
    const float4 xv = ((const float4*)(X + (size_t)row * DD))[threadIdx.x];

    __shared__ float red1[4], red2[4];
    float s = xv.x + xv.y + xv.z + xv.w;
#pragma unroll
    for (int off = 32; off > 0; off >>= 1) s += __shfl_down(s, off);
    const int wave = threadIdx.x >> 6;
    if ((threadIdx.x & 63) == 0) red1[wave] = s;
    __syncthreads();
    const float mu = (red1[0] + red1[1] + red1[2] + red1[3]) * (1.f / DD);

    float dx = xv.x - mu, dy = xv.y - mu, dz = xv.z - mu, dw = xv.w - mu;
    float s2 = dx * dx + dy * dy + dz * dz + dw * dw;
#pragma unroll
    for (int off = 32; off > 0; off >>= 1) s2 += __shfl_down(s2, off);
    if ((threadIdx.x & 63) == 0) red2[wave] = s2;
    __syncthreads();
    const float var = (red2[0] + red2[1] + red2[2] + red2[3]) * (1.f / DD);
    const float rstd = rsqrtf(var + LN_EPS);

    const float4 gv = ((const float4*)g)[threadIdx.x];
    const float4 bv = ((const float4*)bta)[threadIdx.x];
    float4 yv;
    yv.x = dx * rstd * gv.x + bv.x;
    yv.y = dy * rstd * gv.y + bv.y;
    yv.z = dz * rstd * gv.z + bv.z;
    yv.w = dw * rstd * gv.w + bv.w;
    ((float4*)(Y + (size_t)row * DD))[threadIdx.x] = yv;
}

// ---------------------------------------------------------------------------
// Workspace budget (floats), peak 40M floats = 160 MB:
//   [0,       24M) qkvbuf   (phases 2-3)   -- later overwritten by hbuf
//   [24M,     27M) Wq2      (phases 1-2)
//   [32M,     40M) att      (phases 3-4)   -- later reused as out1 (phase 5+)
//   [0,       32M) hbuf     (phases 6-7)
// y and y2 are staged directly in d_out; LN runs in-place on d_out.
// ---------------------------------------------------------------------------
extern "C" void kernel_launch(void* const* d_in, const int* in_sizes, int n_in,
                              void* d_out, int out_size, void* d_ws,
                              size_t ws_size, hipStream_t stream) {
    const float* x     = (const float*)d_in[0];
    const float* Wqkv  = (const float*)d_in[1];
    const float* Wproj = (const float*)d_in[2];
    const float* bproj = (const float*)d_in[3];
    const float* ln1_g = (const float*)d_in[4];
    const float* ln1_b = (const float*)d_in[5];
    const float* ln2_g = (const float*)d_in[6];
    const float* ln2_b = (const float*)d_in[7];
    const float* W1    = (const float*)d_in[8];
    const float* b1    = (const float*)d_in[9];
    const float* W2    = (const float*)d_in[10];
    const float* b2    = (const float*)d_in[11];
    float* out = (float*)d_out;

    const size_t M = (size_t)BB * SS;     // 8192 rows
    const size_t MEG = 1024 * 1024;
    float* ws     = (float*)d_ws;
    float* qkvbuf = ws;                   // 24M floats
    float* Wq2    = ws + 24 * MEG;        // 3M floats
    float* att    = ws + 32 * MEG;        // 8M floats
    float* out1   = ws + 32 * MEG;        // 8M floats (att's slot, att dead)
    float* hbuf   = ws;                   // 32M floats (qkv/Wq2 slots, dead)
    float* y  = out;                      // attn residual sum staged in d_out
    float* y2 = out;                      // MLP residual sum staged in d_out

    // 1. repack Wqkv
    repack_wqkv_kernel<<<(DD * HH * 3 * DHH + 255) / 256, 256, 0, stream>>>(Wqkv, Wq2);

    // 2. QKV GEMM: qkvbuf[M,3072] = x[M,1024] @ Wq2[1024,3072]
    gemm_kernel<0><<<dim3((HH * 3 * DHH) / 64, M / 64), 256, 0, stream>>>(
        x, Wq2, qkvbuf, nullptr, nullptr, (int)M, HH * 3 * DHH, DD);

    // 3. causal attention -> att[M, D]
    attn_kernel<<<dim3(SS / 256, BB * HH), 256, 0, stream>>>(qkvbuf, att);

    // 4. proj GEMM + bias + residual(x): y = att @ Wproj + bproj + x
    gemm_kernel<3><<<dim3(DD / 64, M / 64), 256, 0, stream>>>(
        att, Wproj, y, bproj, x, (int)M, DD, DD);

    // 5. LN1: out1 = LN(y)   (reads d_out, writes ws slot)
    ln_kernel<<<M, 256, 0, stream>>>(y, ln1_g, ln1_b, out1);

    // 6. MLP up + exact GELU: hbuf = gelu(out1 @ W1 + b1)
    gemm_kernel<2><<<dim3(DFF / 64, M / 64), 256, 0, stream>>>(
        out1, W1, hbuf, b1, nullptr, (int)M, DFF, DD);

    // 7. MLP down + bias + residual(out1): y2 = hbuf @ W2 + b2 + out1
    gemm_kernel<3><<<dim3(DD / 64, M / 64), 256, 0, stream>>>(
        hbuf, W2, y2, b2, out1, (int)M, DD, DFF);

    // 8. LN2 in-place on d_out
    ln_kernel<<<M, 256, 0, stream>>>(y2, ln2_g, ln2_b, out);
}

// Round 3
// 2521.164 us; speedup vs baseline: 1.9918x; 1.9918x over previous
//
#include <hip/hip_runtime.h>
#include <math.h>

#define BB 4
#define SS 2048
#define DD 1024
#define HH 16
#define DHH 64
#define DFF 4096
static constexpr float LN_EPS = 1e-5f;

typedef __bf16 bf16x8 __attribute__((ext_vector_type(8)));
typedef float f32x4 __attribute__((ext_vector_type(4)));
typedef unsigned short u16x8 __attribute__((ext_vector_type(8)));

__device__ inline unsigned short f2bf(float f) {
    union { float f; unsigned int u; } v; v.f = f;
    unsigned int u = v.u + 0x7FFFu + ((v.u >> 16) & 1u);  // RNE
    return (unsigned short)(u >> 16);
}

// ---------------------------------------------------------------------------
// fp32 [R][C] -> bf16 transposed [C][R]. 64x64 LDS tiles. R,C multiples of 64.
// ---------------------------------------------------------------------------
__global__ __launch_bounds__(256) void transpose_bf16_kernel(
    const float* __restrict__ in, unsigned short* __restrict__ outT,
    int R, int C) {
    __shared__ float t[64][65];
    const int r0 = blockIdx.y * 64, c0 = blockIdx.x * 64;
    const int cl = threadIdx.x & 63, rl = threadIdx.x >> 6;
#pragma unroll
    for (int rr = 0; rr < 16; ++rr)
        t[rl + rr * 4][cl] = in[(size_t)(r0 + rl + rr * 4) * C + c0 + cl];
    __syncthreads();
#pragma unroll
    for (int rr = 0; rr < 16; ++rr)
        outT[(size_t)(c0 + rl + rr * 4) * R + r0 + cl] = f2bf(t[cl][rl + rr * 4]);
}

// ---------------------------------------------------------------------------
// Wqkv [H][D][192] fp32 -> Wq2T bf16 [3072][1024] where row n=h*192+e, col k=d.
// ---------------------------------------------------------------------------
__global__ __launch_bounds__(256) void repack_wqkv_bf16_kernel(
    const float* __restrict__ Wqkv, unsigned short* __restrict__ Wq2T) {
    __shared__ float t[64][65];
    const int h = blockIdx.z;
    const int d0 = blockIdx.y * 64, e0 = blockIdx.x * 64;
    const int cl = threadIdx.x & 63, rl = threadIdx.x >> 6;
#pragma unroll
    for (int rr = 0; rr < 16; ++rr)
        t[rl + rr * 4][cl] =
            Wqkv[((size_t)h * DD + d0 + rl + rr * 4) * 192 + e0 + cl];
    __syncthreads();
#pragma unroll
    for (int rr = 0; rr < 16; ++rr)
        Wq2T[((size_t)h * 192 + e0 + rl + rr * 4) * DD + d0 + cl] =
            f2bf(t[cl][rl + rr * 4]);
}

// ---------------------------------------------------------------------------
// Straight fp32 -> bf16 convert.
// ---------------------------------------------------------------------------
__global__ __launch_bounds__(256) void f2bf_kernel(
    const float* __restrict__ in, unsigned short* __restrict__ out, int n) {
    int i = blockIdx.x * 256 + threadIdx.x;
    if (i < n) out[i] = f2bf(in[i]);
}

// ---------------------------------------------------------------------------
// bf16 MFMA GEMM: C[M,N] = A[M,K] @ B[K,N], with B supplied TRANSPOSED as
// BT[N,K]. 128x128 tile, 256 threads (4 waves, 2x2 of 64x64), BK=32,
// mfma_f32_16x16x32_bf16, 4x4 accs/wave.
// MODE 0: C fp32 plain. MODE 2: bf16 out = gelu(C + bias). MODE 3: fp32
// out = C + bias + resid.
// Fragment layouts (HW-verified, learn_hip m89/m91): A/B-frag
// [m|n = lane&15][k=(lane>>4)*8+j]; C/D col=lane&15, row=(lane>>4)*4+reg.
// ---------------------------------------------------------------------------
template <int MODE>
__global__ __launch_bounds__(256) void mfma_gemm_kernel(
    const unsigned short* __restrict__ A, const unsigned short* __restrict__ BT,
    float* __restrict__ Cf, unsigned short* __restrict__ Cb,
    const float* __restrict__ bias, const float* __restrict__ resid,
    int M, int N, int K) {
    __shared__ __align__(16) unsigned short Als[128 * 32];
    __shared__ __align__(16) unsigned short Bls[128 * 32];
    const int tid = threadIdx.x;
    const int lane = tid & 63;
    const int wave = tid >> 6;
    const int wr = (wave >> 1) * 64;
    const int wc = (wave & 1) * 64;
    const int row0 = blockIdx.y * 128;
    const int col0 = blockIdx.x * 128;

    const int lr = tid >> 2;          // staging row 0..63
    const int lk = (tid & 3) * 8;     // staging k-offset (elements)

    const int m_lo = lane & 15;
    const int kq8 = (lane >> 4) * 8;

    f32x4 acc[4][4] = {};

    for (int k0 = 0; k0 < K; k0 += 32) {
        u16x8 a0 = *(const u16x8*)&A[(size_t)(row0 + lr) * K + k0 + lk];
        u16x8 a1 = *(const u16x8*)&A[(size_t)(row0 + 64 + lr) * K + k0 + lk];
        u16x8 b0 = *(const u16x8*)&BT[(size_t)(col0 + lr) * K + k0 + lk];
        u16x8 b1 = *(const u16x8*)&BT[(size_t)(col0 + 64 + lr) * K + k0 + lk];
        __syncthreads();   // previous iter's LDS reads done
        *(u16x8*)&Als[lr * 32 + lk] = a0;
        *(u16x8*)&Als[(64 + lr) * 32 + lk] = a1;
        *(u16x8*)&Bls[lr * 32 + lk] = b0;
        *(u16x8*)&Bls[(64 + lr) * 32 + lk] = b1;
        __syncthreads();

        bf16x8 af[4], bfr[4];
#pragma unroll
        for (int i = 0; i < 4; ++i)
            af[i] = __builtin_bit_cast(
                bf16x8, *(const u16x8*)&Als[(wr + i * 16 + m_lo) * 32 + kq8]);
#pragma unroll
        for (int j = 0; j < 4; ++j)
            bfr[j] = __builtin_bit_cast(
                bf16x8, *(const u16x8*)&Bls[(wc + j * 16 + m_lo) * 32 + kq8]);
#pragma unroll
        for (int i = 0; i < 4; ++i)
#pragma unroll
            for (int j = 0; j < 4; ++j)
                acc[i][j] = __builtin_amdgcn_mfma_f32_16x16x32_bf16(
                    af[i], bfr[j], acc[i][j], 0, 0, 0);
    }

    const int r_base = (lane >> 4) * 4;
    const int c_off = lane & 15;
#pragma unroll
    for (int i = 0; i < 4; ++i) {
#pragma unroll
        for (int j = 0; j < 4; ++j) {
            const int col = col0 + wc + j * 16 + c_off;
            float bv = (MODE >= 2) ? bias[col] : 0.f;
#pragma unroll
            for (int r = 0; r < 4; ++r) {
                const int row = row0 + wr + i * 16 + r_base + r;
                float v = acc[i][j][r] + bv;
                if (MODE == 2) {
                    v = 0.5f * v * (1.0f + erff(v * 0.70710678118654752f));
                    Cb[(size_t)row * N + col] = f2bf(v);
                } else if (MODE == 3) {
                    v += resid[(size_t)row * N + col];
                    Cf[(size_t)row * N + col] = v;
                } else {
                    Cf[(size_t)row * N + col] = v;
                }
            }
        }
    }
}

// ---------------------------------------------------------------------------
// Causal attention (unchanged math, fp32 in, bf16 out for the proj GEMM).
// qkv: [B*S, 3072], per (token, head): q|k|v 64 each. 1 thread / query row.
// ---------------------------------------------------------------------------
__global__ __launch_bounds__(256) void attn_kernel(
    const float* __restrict__ qkv, unsigned short* __restrict__ att) {
    const int bh = blockIdx.y;
    const int b = bh / HH;
    const int h = bh % HH;
    const int qi = blockIdx.x * 256 + threadIdx.x;
    const size_t rs = HH * 3 * DHH;  // 3072

    const float* qp = qkv + ((size_t)b * SS + qi) * rs + (size_t)h * (3 * DHH);
    float qreg[DHH];
#pragma unroll
    for (int j = 0; j < 16; ++j) {
        float4 t4 = ((const float4*)qp)[j];
        qreg[4 * j + 0] = t4.x; qreg[4 * j + 1] = t4.y;
        qreg[4 * j + 2] = t4.z; qreg[4 * j + 3] = t4.w;
    }
    float o[DHH];
#pragma unroll
    for (int j = 0; j < DHH; ++j) o[j] = 0.f;

    float m = -INFINITY, l = 0.f;
    const float scale = 0.125f;

    const float* kbase = qkv + ((size_t)b * SS) * rs + (size_t)h * (3 * DHH) + DHH;
    const float* vbase = kbase + DHH;

    for (int t = 0; t <= qi; ++t) {
        const float4* kp = (const float4*)(kbase + (size_t)t * rs);
        float s = 0.f;
#pragma unroll
        for (int j = 0; j < 16; ++j) {
            float4 kk = kp[j];
            s += kk.x * qreg[4 * j + 0] + kk.y * qreg[4 * j + 1] +
                 kk.z * qreg[4 * j + 2] + kk.w * qreg[4 * j + 3];
        }
        s *= scale;
        float mn = fmaxf(m, s);
        float corr = __expf(m - mn);
        float p = __expf(s - mn);
        l = l * corr + p;
        const float4* vp = (const float4*)(vbase + (size_t)t * rs);
#pragma unroll
        for (int j = 0; j < 16; ++j) {
            float4 vv = vp[j];
            o[4 * j + 0] = o[4 * j + 0] * corr + p * vv.x;
            o[4 * j + 1] = o[4 * j + 1] * corr + p * vv.y;
            o[4 * j + 2] = o[4 * j + 2] * corr + p * vv.z;
            o[4 * j + 3] = o[4 * j + 3] * corr + p * vv.w;
        }
        m = mn;
    }
    const float inv = 1.f / l;
    unsigned short* op = att + ((size_t)b * SS + qi) * DD + (size_t)h * DHH;
#pragma unroll
    for (int j = 0; j < 16; ++j) {
        ushort4 r4;
        r4.x = f2bf(o[4 * j + 0] * inv);
        r4.y = f2bf(o[4 * j + 1] * inv);
        r4.z = f2bf(o[4 * j + 2] * inv);
        r4.w = f2bf(o[4 * j + 3] * inv);
        ((ushort4*)op)[j] = r4;
    }
}

// ---------------------------------------------------------------------------
// LayerNorm over D=1024; optional extra bf16 output. In-place safe.
// ---------------------------------------------------------------------------
__global__ __launch_bounds__(256) void ln_kernel(
    const float* __restrict__ X, const float* __restrict__ g,
    const float* __restrict__ bta, float* __restrict__ Y,
    unsigned short* __restrict__ Yb) {
    const int row = blockIdx.x;
    const float4 xv = ((const float4*)(X + (size_t)row * DD))[threadIdx.x];

    __shared__ float red1[4], red2[4];
    float s = xv.x + xv.y + xv.z + xv.w;
#pragma unroll
    for (int off = 32; off > 0; off >>= 1) s += __shfl_down(s, off);
    const int wave = threadIdx.x >> 6;
    if ((threadIdx.x & 63) == 0) red1[wave] = s;
    __syncthreads();
    const float mu = (red1[0] + red1[1] + red1[2] + red1[3]) * (1.f / DD);

    float dx = xv.x - mu, dy = xv.y - mu, dz = xv.z - mu, dw = xv.w - mu;
    float s2 = dx * dx + dy * dy + dz * dz + dw * dw;
#pragma unroll
    for (int off = 32; off > 0; off >>= 1) s2 += __shfl_down(s2, off);
    if ((threadIdx.x & 63) == 0) red2[wave] = s2;
    __syncthreads();
    const float var = (red2[0] + red2[1] + red2[2] + red2[3]) * (1.f / DD);
    const float rstd = rsqrtf(var + LN_EPS);

    const float4 gv = ((const float4*)g)[threadIdx.x];
    const float4 bv = ((const float4*)bta)[threadIdx.x];
    float4 yv;
    yv.x = dx * rstd * gv.x + bv.x;
    yv.y = dy * rstd * gv.y + bv.y;
    yv.z = dz * rstd * gv.z + bv.z;
    yv.w = dw * rstd * gv.w + bv.w;
    ((float4*)(Y + (size_t)row * DD))[threadIdx.x] = yv;
    if (Yb) {
        ushort4 q;
        q.x = f2bf(yv.x); q.y = f2bf(yv.y);
        q.z = f2bf(yv.z); q.w = f2bf(yv.w);
        ((ushort4*)(Yb + (size_t)row * DD))[threadIdx.x] = q;
    }
}

// ---------------------------------------------------------------------------
// Workspace layout (byte offsets, peak 144 MB; 160 MB proven safe in R2):
//   [0,96M)    qkvbuf fp32          (phases 2-3)
//   [0,16M)    out1b  bf16          (phase 5+, qkv dead)
//   [16M,80M)  hbuf   bf16          (phase 6+)
//   [96M,102M) Wq2T   bf16          (phases 1-2)
//   [102M,118M)xb     bf16          (phases 1-2)
//   [96M,112M) att    bf16          (phases 3-4, Wq2T/xb dead)
//   [96M,128M) out1   fp32          (phases 5-7, att/WprojT dead)
//   [118M,120M)WprojT bf16          (phases 1-4)
//   [128M,136M)W1T    bf16          (phases 1-6)
//   [136M,144M)W2T    bf16          (phases 1-7)
// ---------------------------------------------------------------------------
extern "C" void kernel_launch(void* const* d_in, const int* in_sizes, int n_in,
                              void* d_out, int out_size, void* d_ws,
                              size_t ws_size, hipStream_t stream) {
    const float* x     = (const float*)d_in[0];
    const float* Wqkv  = (const float*)d_in[1];
    const float* Wproj = (const float*)d_in[2];
    const float* bproj = (const float*)d_in[3];
    const float* ln1_g = (const float*)d_in[4];
    const float* ln1_b = (const float*)d_in[5];
    const float* ln2_g = (const float*)d_in[6];
    const float* ln2_b = (const float*)d_in[7];
    const float* W1    = (const float*)d_in[8];
    const float* b1    = (const float*)d_in[9];
    const float* W2    = (const float*)d_in[10];
    const float* b2    = (const float*)d_in[11];
    float* out = (float*)d_out;

    const size_t M = (size_t)BB * SS;     // 8192
    const size_t MB = 1024 * 1024;
    char* w = (char*)d_ws;
    float*          qkvbuf = (float*)(w + 0);
    unsigned short* out1b  = (unsigned short*)(w + 0);
    unsigned short* hbuf   = (unsigned short*)(w + 16 * MB);
    unsigned short* Wq2T   = (unsigned short*)(w + 96 * MB);
    unsigned short* xb     = (unsigned short*)(w + 102 * MB);
    unsigned short* att    = (unsigned short*)(w + 96 * MB);
    float*          out1   = (float*)(w + 96 * MB);
    unsigned short* WprojT = (unsigned short*)(w + 118 * MB);
    unsigned short* W1T    = (unsigned short*)(w + 128 * MB);
    unsigned short* W2T    = (unsigned short*)(w + 136 * MB);

    // 1. weight/input conversions
    repack_wqkv_bf16_kernel<<<dim3(3, 16, 16), 256, 0, stream>>>(Wqkv, Wq2T);
    transpose_bf16_kernel<<<dim3(16, 16), 256, 0, stream>>>(Wproj, WprojT, 1024, 1024);
    transpose_bf16_kernel<<<dim3(64, 16), 256, 0, stream>>>(W1, W1T, 1024, 4096);
    transpose_bf16_kernel<<<dim3(16, 64), 256, 0, stream>>>(W2, W2T, 4096, 1024);
    f2bf_kernel<<<(int)((M * DD + 255) / 256), 256, 0, stream>>>(x, xb, (int)(M * DD));

    // 2. QKV GEMM: qkvbuf[M,3072] = xb @ Wq2 (fp32 out)
    mfma_gemm_kernel<0><<<dim3(3072 / 128, M / 128), 256, 0, stream>>>(
        xb, Wq2T, qkvbuf, nullptr, nullptr, nullptr, (int)M, 3072, 1024);

    // 3. causal attention -> att[M,1024] bf16
    attn_kernel<<<dim3(SS / 256, BB * HH), 256, 0, stream>>>(qkvbuf, att);

    // 4. proj GEMM + bias + residual(x) -> d_out fp32
    mfma_gemm_kernel<3><<<dim3(1024 / 128, M / 128), 256, 0, stream>>>(
        att, WprojT, out, nullptr, bproj, x, (int)M, 1024, 1024);

    // 5. LN1 -> out1 fp32 + out1b bf16
    ln_kernel<<<(int)M, 256, 0, stream>>>(out, ln1_g, ln1_b, out1, out1b);

    // 6. MLP up + GELU -> hbuf bf16
    mfma_gemm_kernel<2><<<dim3(4096 / 128, M / 128), 256, 0, stream>>>(
        out1b, W1T, nullptr, hbuf, b1, nullptr, (int)M, 4096, 1024);

    // 7. MLP down + bias + residual(out1) -> d_out fp32
    mfma_gemm_kernel<3><<<dim3(1024 / 128, M / 128), 256, 0, stream>>>(
        hbuf, W2T, out, nullptr, b2, out1, (int)M, 1024, 4096);

    // 8. LN2 in-place on d_out
    ln_kernel<<<(int)M, 256, 0, stream>>>(out, ln2_g, ln2_b, out, nullptr);
}

// Round 4
// 935.770 us; speedup vs baseline: 5.3663x; 2.6942x over previous
//
#include <hip/hip_runtime.h>
#include <math.h>

#define BB 4
#define SS 2048
#define DD 1024
#define HH 16
#define DHH 64
#define DFF 4096
static constexpr float LN_EPS = 1e-5f;

typedef __bf16 bf16x8 __attribute__((ext_vector_type(8)));
typedef float f32x4 __attribute__((ext_vector_type(4)));
typedef unsigned short u16x8 __attribute__((ext_vector_type(8)));

__device__ inline unsigned short f2bf(float f) {
    union { float f; unsigned int u; } v; v.f = f;
    unsigned int u = v.u + 0x7FFFu + ((v.u >> 16) & 1u);  // RNE
    return (unsigned short)(u >> 16);
}

// ---------------------------------------------------------------------------
// fp32 [R][C] -> bf16 transposed [C][R]. 64x64 LDS tiles. R,C multiples of 64.
// ---------------------------------------------------------------------------
__global__ __launch_bounds__(256) void transpose_bf16_kernel(
    const float* __restrict__ in, unsigned short* __restrict__ outT,
    int R, int C) {
    __shared__ float t[64][65];
    const int r0 = blockIdx.y * 64, c0 = blockIdx.x * 64;
    const int cl = threadIdx.x & 63, rl = threadIdx.x >> 6;
#pragma unroll
    for (int rr = 0; rr < 16; ++rr)
        t[rl + rr * 4][cl] = in[(size_t)(r0 + rl + rr * 4) * C + c0 + cl];
    __syncthreads();
#pragma unroll
    for (int rr = 0; rr < 16; ++rr)
        outT[(size_t)(c0 + rl + rr * 4) * R + r0 + cl] = f2bf(t[cl][rl + rr * 4]);
}

// ---------------------------------------------------------------------------
// Wqkv [H][D][192] fp32 -> Wq2T bf16 [3072][1024] where row n=h*192+e, col k=d.
// ---------------------------------------------------------------------------
__global__ __launch_bounds__(256) void repack_wqkv_bf16_kernel(
    const float* __restrict__ Wqkv, unsigned short* __restrict__ Wq2T) {
    __shared__ float t[64][65];
    const int h = blockIdx.z;
    const int d0 = blockIdx.y * 64, e0 = blockIdx.x * 64;
    const int cl = threadIdx.x & 63, rl = threadIdx.x >> 6;
#pragma unroll
    for (int rr = 0; rr < 16; ++rr)
        t[rl + rr * 4][cl] =
            Wqkv[((size_t)h * DD + d0 + rl + rr * 4) * 192 + e0 + cl];
    __syncthreads();
#pragma unroll
    for (int rr = 0; rr < 16; ++rr)
        Wq2T[((size_t)h * 192 + e0 + rl + rr * 4) * DD + d0 + cl] =
            f2bf(t[cl][rl + rr * 4]);
}

// ---------------------------------------------------------------------------
// Straight fp32 -> bf16 convert.
// ---------------------------------------------------------------------------
__global__ __launch_bounds__(256) void f2bf_kernel(
    const float* __restrict__ in, unsigned short* __restrict__ out, int n) {
    int i = blockIdx.x * 256 + threadIdx.x;
    if (i < n) out[i] = f2bf(in[i]);
}

// ---------------------------------------------------------------------------
// bf16 MFMA GEMM: C[M,N] = A[M,K] @ B[K,N], with B supplied TRANSPOSED as
// BT[N,K]. 128x128 tile, 256 threads (4 waves, 2x2 of 64x64), BK=32,
// mfma_f32_16x16x32_bf16, 4x4 accs/wave.
// MODE 0: C fp32 plain. MODE 2: bf16 out = gelu(C + bias). MODE 3: fp32
// out = C + bias + resid.
// ---------------------------------------------------------------------------
template <int MODE>
__global__ __launch_bounds__(256) void mfma_gemm_kernel(
    const unsigned short* __restrict__ A, const unsigned short* __restrict__ BT,
    float* __restrict__ Cf, unsigned short* __restrict__ Cb,
    const float* __restrict__ bias, const float* __restrict__ resid,
    int M, int N, int K) {
    __shared__ __align__(16) unsigned short Als[128 * 32];
    __shared__ __align__(16) unsigned short Bls[128 * 32];
    const int tid = threadIdx.x;
    const int lane = tid & 63;
    const int wave = tid >> 6;
    const int wr = (wave >> 1) * 64;
    const int wc = (wave & 1) * 64;
    const int row0 = blockIdx.y * 128;
    const int col0 = blockIdx.x * 128;

    const int lr = tid >> 2;          // staging row 0..63
    const int lk = (tid & 3) * 8;     // staging k-offset (elements)

    const int m_lo = lane & 15;
    const int kq8 = (lane >> 4) * 8;

    f32x4 acc[4][4] = {};

    for (int k0 = 0; k0 < K; k0 += 32) {
        u16x8 a0 = *(const u16x8*)&A[(size_t)(row0 + lr) * K + k0 + lk];
        u16x8 a1 = *(const u16x8*)&A[(size_t)(row0 + 64 + lr) * K + k0 + lk];
        u16x8 b0 = *(const u16x8*)&BT[(size_t)(col0 + lr) * K + k0 + lk];
        u16x8 b1 = *(const u16x8*)&BT[(size_t)(col0 + 64 + lr) * K + k0 + lk];
        __syncthreads();   // previous iter's LDS reads done
        *(u16x8*)&Als[lr * 32 + lk] = a0;
        *(u16x8*)&Als[(64 + lr) * 32 + lk] = a1;
        *(u16x8*)&Bls[lr * 32 + lk] = b0;
        *(u16x8*)&Bls[(64 + lr) * 32 + lk] = b1;
        __syncthreads();

        bf16x8 af[4], bfr[4];
#pragma unroll
        for (int i = 0; i < 4; ++i)
            af[i] = __builtin_bit_cast(
                bf16x8, *(const u16x8*)&Als[(wr + i * 16 + m_lo) * 32 + kq8]);
#pragma unroll
        for (int j = 0; j < 4; ++j)
            bfr[j] = __builtin_bit_cast(
                bf16x8, *(const u16x8*)&Bls[(wc + j * 16 + m_lo) * 32 + kq8]);
#pragma unroll
        for (int i = 0; i < 4; ++i)
#pragma unroll
            for (int j = 0; j < 4; ++j)
                acc[i][j] = __builtin_amdgcn_mfma_f32_16x16x32_bf16(
                    af[i], bfr[j], acc[i][j], 0, 0, 0);
    }

    const int r_base = (lane >> 4) * 4;
    const int c_off = lane & 15;
#pragma unroll
    for (int i = 0; i < 4; ++i) {
#pragma unroll
        for (int j = 0; j < 4; ++j) {
            const int col = col0 + wc + j * 16 + c_off;
            float bv = (MODE >= 2) ? bias[col] : 0.f;
#pragma unroll
            for (int r = 0; r < 4; ++r) {
                const int row = row0 + wr + i * 16 + r_base + r;
                float v = acc[i][j][r] + bv;
                if (MODE == 2) {
                    v = 0.5f * v * (1.0f + erff(v * 0.70710678118654752f));
                    Cb[(size_t)row * N + col] = f2bf(v);
                } else if (MODE == 3) {
                    v += resid[(size_t)row * N + col];
                    Cf[(size_t)row * N + col] = v;
                } else {
                    Cf[(size_t)row * N + col] = v;
                }
            }
        }
    }
}

// ---------------------------------------------------------------------------
// Flash-style causal attention with MFMA.
// Block: 128 q-rows of one (b,h); 4 waves x 32 q-rows. kv tiles of 64.
// qkv fp32 [B*S][3072] (per head: q|k|v 64 each). Output att bf16 [B*S][1024].
// LDS (u16 elems): Pls 128x80 (also Q staging @stride 68), Kls 64x68,
//                  VTls 64x80. Total 39424 B.
// ---------------------------------------------------------------------------
__global__ __launch_bounds__(256) void fattn_kernel(
    const float* __restrict__ qkv, unsigned short* __restrict__ att) {
    __shared__ __align__(16) unsigned short lds[128 * 80 + 64 * 68 + 64 * 80];
    unsigned short* Pls = lds;                 // stride 80 (P) / 68 (Q stage)
    unsigned short* Kls = lds + 128 * 80;      // stride 68
    unsigned short* VTls = Kls + 64 * 68;      // stride 80

    const int qt = blockIdx.x;
    const int bh = blockIdx.y;
    const int b = bh >> 4, h = bh & 15;
    const int q0 = qt * 128;
    const int tid = threadIdx.x;
    const int lane = tid & 63;
    const int wave = tid >> 6;
    const int l15 = lane & 15;
    const int g = lane >> 4;

    const float* qkbase = qkv + (size_t)b * SS * 3072 + h * 192;

    // ---- stage Q (scaled by 1/8) into Pls region, stride 68 ----
    {
        const int row = tid >> 1, c0 = (tid & 1) * 32;
        const float* src = qkbase + (size_t)(q0 + row) * 3072 + c0;
#pragma unroll
        for (int c = 0; c < 32; c += 8) {
            float4 f0 = *(const float4*)(src + c);
            float4 f1 = *(const float4*)(src + c + 4);
            u16x8 pk;
            pk[0] = f2bf(f0.x * 0.125f); pk[1] = f2bf(f0.y * 0.125f);
            pk[2] = f2bf(f0.z * 0.125f); pk[3] = f2bf(f0.w * 0.125f);
            pk[4] = f2bf(f1.x * 0.125f); pk[5] = f2bf(f1.y * 0.125f);
            pk[6] = f2bf(f1.z * 0.125f); pk[7] = f2bf(f1.w * 0.125f);
            *(u16x8*)&Pls[row * 68 + c0 + c] = pk;
        }
    }
    __syncthreads();
    bf16x8 qf[2][2];
#pragma unroll
    for (int i = 0; i < 2; ++i)
#pragma unroll
        for (int ks = 0; ks < 2; ++ks)
            qf[i][ks] = __builtin_bit_cast(
                bf16x8, *(const u16x8*)&Pls[(wave * 32 + i * 16 + l15) * 68 +
                                            ks * 32 + g * 8]);
    __syncthreads();  // Q region dead; Pls now owned per-wave for P

    f32x4 oacc[2][4] = {};
    float mst[2][4], lst[2][4];
#pragma unroll
    for (int i = 0; i < 2; ++i)
#pragma unroll
        for (int r = 0; r < 4; ++r) { mst[i][r] = -1e30f; lst[i][r] = 0.f; }

    const int srow = tid >> 2, sc0 = (tid & 3) * 16, sq = tid & 3;

    for (int t0 = 0; t0 <= q0 + 64; t0 += 64) {
        __syncthreads();  // prev iter's K/VT frag reads done
        // ---- stage K tile [64 kv][64 dh] ----
        {
            const float* src = qkbase + (size_t)(t0 + srow) * 3072 + 64 + sc0;
#pragma unroll
            for (int c = 0; c < 16; c += 8) {
                float4 f0 = *(const float4*)(src + c);
                float4 f1 = *(const float4*)(src + c + 4);
                u16x8 pk;
                pk[0] = f2bf(f0.x); pk[1] = f2bf(f0.y);
                pk[2] = f2bf(f0.z); pk[3] = f2bf(f0.w);
                pk[4] = f2bf(f1.x); pk[5] = f2bf(f1.y);
                pk[6] = f2bf(f1.z); pk[7] = f2bf(f1.w);
                *(u16x8*)&Kls[srow * 68 + sc0 + c] = pk;
            }
        }
        // ---- stage V transposed: VTls[dh][kv], rotated write order ----
        {
            const float* src = qkbase + (size_t)(t0 + srow) * 3072 + 128 + sc0;
            float v[16];
#pragma unroll
            for (int c = 0; c < 16; c += 4) {
                float4 f = *(const float4*)(src + c);
                v[c] = f.x; v[c + 1] = f.y; v[c + 2] = f.z; v[c + 3] = f.w;
            }
#pragma unroll
            for (int c = 0; c < 16; ++c) {
                const int cc = (c + srow + sq) & 15;
                VTls[(sc0 + cc) * 80 + srow] = f2bf(v[cc]);
            }
        }
        __syncthreads();

        // ---- scores: S = Q K^T (scale folded into Q) ----
        f32x4 sacc[2][4] = {};
#pragma unroll
        for (int ks = 0; ks < 2; ++ks) {
            bf16x8 kb[4];
#pragma unroll
            for (int j = 0; j < 4; ++j)
                kb[j] = __builtin_bit_cast(
                    bf16x8, *(const u16x8*)&Kls[(j * 16 + l15) * 68 + ks * 32 +
                                                g * 8]);
#pragma unroll
            for (int i = 0; i < 2; ++i)
#pragma unroll
                for (int j = 0; j < 4; ++j)
                    sacc[i][j] = __builtin_amdgcn_mfma_f32_16x16x32_bf16(
                        qf[i][ks], kb[j], sacc[i][j], 0, 0, 0);
        }

        // ---- causal mask (only tiles straddling the diagonal) ----
        if (t0 >= q0) {
#pragma unroll
            for (int i = 0; i < 2; ++i)
#pragma unroll
                for (int j = 0; j < 4; ++j)
#pragma unroll
                    for (int r = 0; r < 4; ++r) {
                        const int qg = q0 + wave * 32 + i * 16 + g * 4 + r;
                        const int kg = t0 + j * 16 + l15;
                        if (kg > qg) sacc[i][j][r] = -1e30f;
                    }
        }

        // ---- online softmax; write P (bf16) to Pls ----
#pragma unroll
        for (int i = 0; i < 2; ++i) {
#pragma unroll
            for (int r = 0; r < 4; ++r) {
                float mx = sacc[i][0][r];
                mx = fmaxf(mx, sacc[i][1][r]);
                mx = fmaxf(mx, sacc[i][2][r]);
                mx = fmaxf(mx, sacc[i][3][r]);
                mx = fmaxf(mx, __shfl_xor(mx, 1));
                mx = fmaxf(mx, __shfl_xor(mx, 2));
                mx = fmaxf(mx, __shfl_xor(mx, 4));
                mx = fmaxf(mx, __shfl_xor(mx, 8));
                const float mn = fmaxf(mst[i][r], mx);
                const float al = __expf(mst[i][r] - mn);
                mst[i][r] = mn;
                const int prow = (wave * 32 + i * 16 + g * 4 + r) * 80;
                float rsum = 0.f;
#pragma unroll
                for (int j = 0; j < 4; ++j) {
                    const float p = __expf(sacc[i][j][r] - mn);
                    rsum += p;
                    Pls[prow + j * 16 + l15] = f2bf(p);
                }
                rsum += __shfl_xor(rsum, 1);
                rsum += __shfl_xor(rsum, 2);
                rsum += __shfl_xor(rsum, 4);
                rsum += __shfl_xor(rsum, 8);
                lst[i][r] = lst[i][r] * al + rsum;
#pragma unroll
                for (int jo = 0; jo < 4; ++jo) oacc[i][jo][r] *= al;
            }
        }

        // ---- O += P V ----
#pragma unroll
        for (int ks = 0; ks < 2; ++ks) {
            bf16x8 pf[2], vb[4];
#pragma unroll
            for (int i = 0; i < 2; ++i)
                pf[i] = __builtin_bit_cast(
                    bf16x8, *(const u16x8*)&Pls[(wave * 32 + i * 16 + l15) * 80 +
                                                ks * 32 + g * 8]);
#pragma unroll
            for (int jo = 0; jo < 4; ++jo)
                vb[jo] = __builtin_bit_cast(
                    bf16x8, *(const u16x8*)&VTls[(jo * 16 + l15) * 80 + ks * 32 +
                                                 g * 8]);
#pragma unroll
            for (int i = 0; i < 2; ++i)
#pragma unroll
                for (int jo = 0; jo < 4; ++jo)
                    oacc[i][jo] = __builtin_amdgcn_mfma_f32_16x16x32_bf16(
                        pf[i], vb[jo], oacc[i][jo], 0, 0, 0);
        }
    }

    // ---- epilogue: O / l -> att bf16 ----
#pragma unroll
    for (int i = 0; i < 2; ++i) {
#pragma unroll
        for (int r = 0; r < 4; ++r) {
            const float inv = 1.f / lst[i][r];
            const int qg = q0 + wave * 32 + i * 16 + g * 4 + r;
            unsigned short* dst =
                att + ((size_t)b * SS + qg) * DD + h * 64;
#pragma unroll
            for (int jo = 0; jo < 4; ++jo)
                dst[jo * 16 + l15] = f2bf(oacc[i][jo][r] * inv);
        }
    }
}

// ---------------------------------------------------------------------------
// LayerNorm over D=1024; optional extra bf16 output. In-place safe.
// ---------------------------------------------------------------------------
__global__ __launch_bounds__(256) void ln_kernel(
    const float* __restrict__ X, const float* __restrict__ g,
    const float* __restrict__ bta, float* __restrict__ Y,
    unsigned short* __restrict__ Yb) {
    const int row = blockIdx.x;
    const float4 xv = ((const float4*)(X + (size_t)row * DD))[threadIdx.x];

    __shared__ float red1[4], red2[4];
    float s = xv.x + xv.y + xv.z + xv.w;
#pragma unroll
    for (int off = 32; off > 0; off >>= 1) s += __shfl_down(s, off);
    const int wave = threadIdx.x >> 6;
    if ((threadIdx.x & 63) == 0) red1[wave] = s;
    __syncthreads();
    const float mu = (red1[0] + red1[1] + red1[2] + red1[3]) * (1.f / DD);

    float dx = xv.x - mu, dy = xv.y - mu, dz = xv.z - mu, dw = xv.w - mu;
    float s2 = dx * dx + dy * dy + dz * dz + dw * dw;
#pragma unroll
    for (int off = 32; off > 0; off >>= 1) s2 += __shfl_down(s2, off);
    if ((threadIdx.x & 63) == 0) red2[wave] = s2;
    __syncthreads();
    const float var = (red2[0] + red2[1] + red2[2] + red2[3]) * (1.f / DD);
    const float rstd = rsqrtf(var + LN_EPS);

    const float4 gv = ((const float4*)g)[threadIdx.x];
    const float4 bv = ((const float4*)bta)[threadIdx.x];
    float4 yv;
    yv.x = dx * rstd * gv.x + bv.x;
    yv.y = dy * rstd * gv.y + bv.y;
    yv.z = dz * rstd * gv.z + bv.z;
    yv.w = dw * rstd * gv.w + bv.w;
    ((float4*)(Y + (size_t)row * DD))[threadIdx.x] = yv;
    if (Yb) {
        ushort4 q;
        q.x = f2bf(yv.x); q.y = f2bf(yv.y);
        q.z = f2bf(yv.z); q.w = f2bf(yv.w);
        ((ushort4*)(Yb + (size_t)row * DD))[threadIdx.x] = q;
    }
}

// ---------------------------------------------------------------------------
// Workspace layout (byte offsets, peak 144 MB):
//   [0,96M)    qkvbuf fp32          (phases 2-3)
//   [0,16M)    out1b  bf16          (phase 5+, qkv dead)
//   [16M,80M)  hbuf   bf16          (phase 6+)
//   [96M,102M) Wq2T   bf16          (phases 1-2)
//   [102M,118M)xb     bf16          (phases 1-2)
//   [96M,112M) att    bf16          (phases 3-4, Wq2T/xb dead)
//   [96M,128M) out1   fp32          (phases 5-7)
//   [118M,120M)WprojT bf16          (phases 1-4)
//   [128M,136M)W1T    bf16          (phases 1-6)
//   [136M,144M)W2T    bf16          (phases 1-7)
// ---------------------------------------------------------------------------
extern "C" void kernel_launch(void* const* d_in, const int* in_sizes, int n_in,
                              void* d_out, int out_size, void* d_ws,
                              size_t ws_size, hipStream_t stream) {
    const float* x     = (const float*)d_in[0];
    const float* Wqkv  = (const float*)d_in[1];
    const float* Wproj = (const float*)d_in[2];
    const float* bproj = (const float*)d_in[3];
    const float* ln1_g = (const float*)d_in[4];
    const float* ln1_b = (const float*)d_in[5];
    const float* ln2_g = (const float*)d_in[6];
    const float* ln2_b = (const float*)d_in[7];
    const float* W1    = (const float*)d_in[8];
    const float* b1    = (const float*)d_in[9];
    const float* W2    = (const float*)d_in[10];
    const float* b2    = (const float*)d_in[11];
    float* out = (float*)d_out;

    const size_t M = (size_t)BB * SS;     // 8192
    const size_t MB = 1024 * 1024;
    char* w = (char*)d_ws;
    float*          qkvbuf = (float*)(w + 0);
    unsigned short* out1b  = (unsigned short*)(w + 0);
    unsigned short* hbuf   = (unsigned short*)(w + 16 * MB);
    unsigned short* Wq2T   = (unsigned short*)(w + 96 * MB);
    unsigned short* xb     = (unsigned short*)(w + 102 * MB);
    unsigned short* att    = (unsigned short*)(w + 96 * MB);
    float*          out1   = (float*)(w + 96 * MB);
    unsigned short* WprojT = (unsigned short*)(w + 118 * MB);
    unsigned short* W1T    = (unsigned short*)(w + 128 * MB);
    unsigned short* W2T    = (unsigned short*)(w + 136 * MB);

    // 1. weight/input conversions
    repack_wqkv_bf16_kernel<<<dim3(3, 16, 16), 256, 0, stream>>>(Wqkv, Wq2T);
    transpose_bf16_kernel<<<dim3(16, 16), 256, 0, stream>>>(Wproj, WprojT, 1024, 1024);
    transpose_bf16_kernel<<<dim3(64, 16), 256, 0, stream>>>(W1, W1T, 1024, 4096);
    transpose_bf16_kernel<<<dim3(16, 64), 256, 0, stream>>>(W2, W2T, 4096, 1024);
    f2bf_kernel<<<(int)((M * DD + 255) / 256), 256, 0, stream>>>(x, xb, (int)(M * DD));

    // 2. QKV GEMM: qkvbuf[M,3072] = xb @ Wq2 (fp32 out)
    mfma_gemm_kernel<0><<<dim3(3072 / 128, M / 128), 256, 0, stream>>>(
        xb, Wq2T, qkvbuf, nullptr, nullptr, nullptr, (int)M, 3072, 1024);

    // 3. flash causal attention -> att[M,1024] bf16
    fattn_kernel<<<dim3(SS / 128, BB * HH), 256, 0, stream>>>(qkvbuf, att);

    // 4. proj GEMM + bias + residual(x) -> d_out fp32
    mfma_gemm_kernel<3><<<dim3(1024 / 128, M / 128), 256, 0, stream>>>(
        att, WprojT, out, nullptr, bproj, x, (int)M, 1024, 1024);

    // 5. LN1 -> out1 fp32 + out1b bf16
    ln_kernel<<<(int)M, 256, 0, stream>>>(out, ln1_g, ln1_b, out1, out1b);

    // 6. MLP up + GELU -> hbuf bf16
    mfma_gemm_kernel<2><<<dim3(4096 / 128, M / 128), 256, 0, stream>>>(
        out1b, W1T, nullptr, hbuf, b1, nullptr, (int)M, 4096, 1024);

    // 7. MLP down + bias + residual(out1) -> d_out fp32
    mfma_gemm_kernel<3><<<dim3(1024 / 128, M / 128), 256, 0, stream>>>(
        hbuf, W2T, out, nullptr, b2, out1, (int)M, 1024, 4096);

    // 8. LN2 in-place on d_out
    ln_kernel<<<(int)M, 256, 0, stream>>>(out, ln2_g, ln2_b, out, nullptr);
}

// Round 5
// 661.062 us; speedup vs baseline: 7.5962x; 1.4156x over previous
//
#include <hip/hip_runtime.h>
#include <math.h>

#define BB 4
#define SS 2048
#define DD 1024
#define HH 16
#define DHH 64
#define DFF 4096
static constexpr float LN_EPS = 1e-5f;

typedef __bf16 bf16x8 __attribute__((ext_vector_type(8)));
typedef float f32x4 __attribute__((ext_vector_type(4)));
typedef unsigned short u16x8 __attribute__((ext_vector_type(8)));

__device__ inline unsigned short f2bf(float f) {
    union { float f; unsigned int u; } v; v.f = f;
    unsigned int u = v.u + 0x7FFFu + ((v.u >> 16) & 1u);  // RNE
    return (unsigned short)(u >> 16);
}

// ---------------------------------------------------------------------------
// fp32 [R][C] -> bf16 transposed [C][R]. 64x64 LDS tiles.
// ---------------------------------------------------------------------------
__global__ __launch_bounds__(256) void transpose_bf16_kernel(
    const float* __restrict__ in, unsigned short* __restrict__ outT,
    int R, int C) {
    __shared__ float t[64][65];
    const int r0 = blockIdx.y * 64, c0 = blockIdx.x * 64;
    const int cl = threadIdx.x & 63, rl = threadIdx.x >> 6;
#pragma unroll
    for (int rr = 0; rr < 16; ++rr)
        t[rl + rr * 4][cl] = in[(size_t)(r0 + rl + rr * 4) * C + c0 + cl];
    __syncthreads();
#pragma unroll
    for (int rr = 0; rr < 16; ++rr)
        outT[(size_t)(c0 + rl + rr * 4) * R + r0 + cl] = f2bf(t[cl][rl + rr * 4]);
}

// ---------------------------------------------------------------------------
// Wqkv [H][D][192] fp32 -> Wq2T bf16 [3072][1024] (row n=h*192+e, col k=d).
// ---------------------------------------------------------------------------
__global__ __launch_bounds__(256) void repack_wqkv_bf16_kernel(
    const float* __restrict__ Wqkv, unsigned short* __restrict__ Wq2T) {
    __shared__ float t[64][65];
    const int h = blockIdx.z;
    const int d0 = blockIdx.y * 64, e0 = blockIdx.x * 64;
    const int cl = threadIdx.x & 63, rl = threadIdx.x >> 6;
#pragma unroll
    for (int rr = 0; rr < 16; ++rr)
        t[rl + rr * 4][cl] =
            Wqkv[((size_t)h * DD + d0 + rl + rr * 4) * 192 + e0 + cl];
    __syncthreads();
#pragma unroll
    for (int rr = 0; rr < 16; ++rr)
        Wq2T[((size_t)h * 192 + e0 + rl + rr * 4) * DD + d0 + cl] =
            f2bf(t[cl][rl + rr * 4]);
}

__global__ __launch_bounds__(256) void f2bf_kernel(
    const float* __restrict__ in, unsigned short* __restrict__ out, int n) {
    int i = blockIdx.x * 256 + threadIdx.x;
    if (i < n) out[i] = f2bf(in[i]);
}

// ---------------------------------------------------------------------------
// bf16 MFMA GEMM: C[M,N] = A[M,K] @ BT[N,K]^T. 128x128 tile, 4 waves, BK=32.
// MODE 2: bf16 out = gelu(C+bias). MODE 3: fp32 out = C+bias+resid.
// MODE 4 (QKV): scatter bf16 into flash layouts Qb[bh][s][64] (x0.125),
//               Kb[bh][s][64], VTb[bh][64][s] (transposed, packed ushort4).
// ---------------------------------------------------------------------------
template <int MODE>
__global__ __launch_bounds__(256) void mfma_gemm_kernel(
    const unsigned short* __restrict__ A, const unsigned short* __restrict__ BT,
    float* __restrict__ Cf, unsigned short* __restrict__ Cb,
    const float* __restrict__ bias, const float* __restrict__ resid,
    unsigned short* __restrict__ Qb, unsigned short* __restrict__ Kb,
    unsigned short* __restrict__ VTb, int M, int N, int K) {
    __shared__ __align__(16) unsigned short Als[128 * 32];
    __shared__ __align__(16) unsigned short Bls[128 * 32];
    const int tid = threadIdx.x;
    const int lane = tid & 63;
    const int wave = tid >> 6;
    const int wr = (wave >> 1) * 64;
    const int wc = (wave & 1) * 64;
    const int row0 = blockIdx.y * 128;
    const int col0 = blockIdx.x * 128;

    const int lr = tid >> 2;
    const int lk = (tid & 3) * 8;
    const int m_lo = lane & 15;
    const int kq8 = (lane >> 4) * 8;

    f32x4 acc[4][4] = {};

    for (int k0 = 0; k0 < K; k0 += 32) {
        u16x8 a0 = *(const u16x8*)&A[(size_t)(row0 + lr) * K + k0 + lk];
        u16x8 a1 = *(const u16x8*)&A[(size_t)(row0 + 64 + lr) * K + k0 + lk];
        u16x8 b0 = *(const u16x8*)&BT[(size_t)(col0 + lr) * K + k0 + lk];
        u16x8 b1 = *(const u16x8*)&BT[(size_t)(col0 + 64 + lr) * K + k0 + lk];
        __syncthreads();
        *(u16x8*)&Als[lr * 32 + lk] = a0;
        *(u16x8*)&Als[(64 + lr) * 32 + lk] = a1;
        *(u16x8*)&Bls[lr * 32 + lk] = b0;
        *(u16x8*)&Bls[(64 + lr) * 32 + lk] = b1;
        __syncthreads();

        bf16x8 af[4], bfr[4];
#pragma unroll
        for (int i = 0; i < 4; ++i)
            af[i] = __builtin_bit_cast(
                bf16x8, *(const u16x8*)&Als[(wr + i * 16 + m_lo) * 32 + kq8]);
#pragma unroll
        for (int j = 0; j < 4; ++j)
            bfr[j] = __builtin_bit_cast(
                bf16x8, *(const u16x8*)&Bls[(wc + j * 16 + m_lo) * 32 + kq8]);
#pragma unroll
        for (int i = 0; i < 4; ++i)
#pragma unroll
            for (int j = 0; j < 4; ++j)
                acc[i][j] = __builtin_amdgcn_mfma_f32_16x16x32_bf16(
                    af[i], bfr[j], acc[i][j], 0, 0, 0);
    }

    const int r_base = (lane >> 4) * 4;
    const int c_off = lane & 15;
#pragma unroll
    for (int i = 0; i < 4; ++i) {
#pragma unroll
        for (int j = 0; j < 4; ++j) {
            const int col = col0 + wc + j * 16 + c_off;
            const int rowb = row0 + wr + i * 16 + r_base;
            if (MODE == 4) {
                // col block (16-wide, 16-aligned) lies in one 64-segment
                const int h = col / 192, e = col % 192;
                const int bb = rowb >> 11, s = rowb & 2047;
                if (e < 64) {
                    unsigned short* q =
                        Qb + (((size_t)bb * HH + h) * SS + s) * 64 + e;
#pragma unroll
                    for (int r = 0; r < 4; ++r)
                        q[r * 64] = f2bf(acc[i][j][r] * 0.125f);
                } else if (e < 128) {
                    unsigned short* kp =
                        Kb + (((size_t)bb * HH + h) * SS + s) * 64 + (e - 64);
#pragma unroll
                    for (int r = 0; r < 4; ++r)
                        kp[r * 64] = f2bf(acc[i][j][r]);
                } else {
                    ushort4 pk;
                    pk.x = f2bf(acc[i][j][0]);
                    pk.y = f2bf(acc[i][j][1]);
                    pk.z = f2bf(acc[i][j][2]);
                    pk.w = f2bf(acc[i][j][3]);
                    *(ushort4*)(VTb + (((size_t)bb * HH + h) * 64 + (e - 128)) *
                                          SS + s) = pk;
                }
            } else {
                const float bv = bias[col];
#pragma unroll
                for (int r = 0; r < 4; ++r) {
                    const int row = rowb + r;
                    float v = acc[i][j][r] + bv;
                    if (MODE == 2) {
                        v = 0.5f * v * (1.0f + erff(v * 0.70710678118654752f));
                        Cb[(size_t)row * N + col] = f2bf(v);
                    } else {
                        v += resid[(size_t)row * N + col];
                        Cf[(size_t)row * N + col] = v;
                    }
                }
            }
        }
    }
}

// ---------------------------------------------------------------------------
// Flash causal attention, all-bf16 staging from pre-routed layouts.
// Block: 128 q-rows of one (b,h); 4 waves x 32 rows; kv tiles of 64.
// Grid: x = bh (64) for CU load balance, y = q-tile (16).
// ---------------------------------------------------------------------------
__global__ __launch_bounds__(256) void fattn_kernel(
    const unsigned short* __restrict__ Qb, const unsigned short* __restrict__ Kb,
    const unsigned short* __restrict__ VTb, unsigned short* __restrict__ att) {
    constexpr int QSTR = 68, KSTR = 68, VSTR = 76, PSTR = 84;
    __shared__ __align__(16) unsigned short Pls[128 * PSTR];   // 21504 B
    __shared__ __align__(16) unsigned short Kls[64 * KSTR];    //  8704 B
    __shared__ __align__(16) unsigned short VTls[64 * VSTR];   //  9728 B

    const int bh = blockIdx.x;
    const int q0 = blockIdx.y * 128;
    const int tid = threadIdx.x;
    const int lane = tid & 63;
    const int wave = tid >> 6;
    const int l15 = lane & 15;
    const int g = lane >> 4;
    const int b = bh >> 4, h = bh & 15;

    const unsigned short* Qh = Qb + (size_t)bh * SS * 64;
    const unsigned short* Kh = Kb + (size_t)bh * SS * 64;
    const unsigned short* Vh = VTb + (size_t)bh * 64 * SS;

    // ---- stage Q tile (already scaled) ----
    {
        const int row = tid >> 1, c0 = (tid & 1) * 32;
        const unsigned short* src = Qh + (size_t)(q0 + row) * 64 + c0;
        unsigned short* dst = &Pls[row * QSTR + c0];
#pragma unroll
        for (int c = 0; c < 32; c += 8)
            *(u16x8*)(dst + c) = *(const u16x8*)(src + c);
    }
    __syncthreads();
    bf16x8 qf[2][2];
#pragma unroll
    for (int i = 0; i < 2; ++i)
#pragma unroll
        for (int ks = 0; ks < 2; ++ks)
            qf[i][ks] = __builtin_bit_cast(
                bf16x8, *(const u16x8*)&Pls[(wave * 32 + i * 16 + l15) * QSTR +
                                            ks * 32 + g * 8]);
    __syncthreads();

    f32x4 oacc[2][4] = {};
    float mst[2][4], lst[2][4];
#pragma unroll
    for (int i = 0; i < 2; ++i)
#pragma unroll
        for (int r = 0; r < 4; ++r) { mst[i][r] = -1e30f; lst[i][r] = 0.f; }

    const int srow = tid >> 2, sc0 = (tid & 3) * 16;
    const int qlim = q0 + wave * 32 + 31;   // last q-row this wave owns

    for (int t0 = 0; t0 <= q0 + 64; t0 += 64) {
        __syncthreads();  // prev iter frag reads done
        {
            const unsigned short* ksrc = Kh + (size_t)(t0 + srow) * 64 + sc0;
            *(u16x8*)&Kls[srow * KSTR + sc0]     = *(const u16x8*)ksrc;
            *(u16x8*)&Kls[srow * KSTR + sc0 + 8] = *(const u16x8*)(ksrc + 8);
            const unsigned short* vsrc = Vh + (size_t)srow * SS + t0 + sc0;
            *(u16x8*)&VTls[srow * VSTR + sc0]     = *(const u16x8*)vsrc;
            *(u16x8*)&VTls[srow * VSTR + sc0 + 8] = *(const u16x8*)(vsrc + 8);
        }
        __syncthreads();
        if (t0 > qlim) continue;   // fully masked for this wave (uniform)

        // ---- S = Q K^T ----
        f32x4 sacc[2][4] = {};
#pragma unroll
        for (int ks = 0; ks < 2; ++ks) {
            bf16x8 kb[4];
#pragma unroll
            for (int j = 0; j < 4; ++j)
                kb[j] = __builtin_bit_cast(
                    bf16x8, *(const u16x8*)&Kls[(j * 16 + l15) * KSTR +
                                                ks * 32 + g * 8]);
#pragma unroll
            for (int i = 0; i < 2; ++i)
#pragma unroll
                for (int j = 0; j < 4; ++j)
                    sacc[i][j] = __builtin_amdgcn_mfma_f32_16x16x32_bf16(
                        qf[i][ks], kb[j], sacc[i][j], 0, 0, 0);
        }

        // ---- causal mask ----
        if (t0 >= q0) {
#pragma unroll
            for (int i = 0; i < 2; ++i)
#pragma unroll
                for (int j = 0; j < 4; ++j)
#pragma unroll
                    for (int r = 0; r < 4; ++r) {
                        const int qg = q0 + wave * 32 + i * 16 + g * 4 + r;
                        const int kg = t0 + j * 16 + l15;
                        if (kg > qg) sacc[i][j][r] = -1e30f;
                    }
        }

        // ---- online softmax; P -> LDS ----
#pragma unroll
        for (int i = 0; i < 2; ++i) {
#pragma unroll
            for (int r = 0; r < 4; ++r) {
                float mx = fmaxf(fmaxf(sacc[i][0][r], sacc[i][1][r]),
                                 fmaxf(sacc[i][2][r], sacc[i][3][r]));
                mx = fmaxf(mx, __shfl_xor(mx, 1));
                mx = fmaxf(mx, __shfl_xor(mx, 2));
                mx = fmaxf(mx, __shfl_xor(mx, 4));
                mx = fmaxf(mx, __shfl_xor(mx, 8));
                const float mn = fmaxf(mst[i][r], mx);
                const float al = __expf(mst[i][r] - mn);
                mst[i][r] = mn;
                const int prow = (wave * 32 + i * 16 + g * 4 + r) * PSTR;
                float rsum = 0.f;
#pragma unroll
                for (int j = 0; j < 4; ++j) {
                    const float p = __expf(sacc[i][j][r] - mn);
                    rsum += p;
                    Pls[prow + j * 16 + l15] = f2bf(p);
                }
                rsum += __shfl_xor(rsum, 1);
                rsum += __shfl_xor(rsum, 2);
                rsum += __shfl_xor(rsum, 4);
                rsum += __shfl_xor(rsum, 8);
                lst[i][r] = lst[i][r] * al + rsum;
#pragma unroll
                for (int jo = 0; jo < 4; ++jo) oacc[i][jo][r] *= al;
            }
        }

        // ---- O += P V ----
#pragma unroll
        for (int ks = 0; ks < 2; ++ks) {
            bf16x8 pf[2], vb[4];
#pragma unroll
            for (int i = 0; i < 2; ++i)
                pf[i] = __builtin_bit_cast(
                    bf16x8, *(const u16x8*)&Pls[(wave * 32 + i * 16 + l15) *
                                                PSTR + ks * 32 + g * 8]);
#pragma unroll
            for (int jo = 0; jo < 4; ++jo)
                vb[jo] = __builtin_bit_cast(
                    bf16x8, *(const u16x8*)&VTls[(jo * 16 + l15) * VSTR +
                                                 ks * 32 + g * 8]);
#pragma unroll
            for (int i = 0; i < 2; ++i)
#pragma unroll
                for (int jo = 0; jo < 4; ++jo)
                    oacc[i][jo] = __builtin_amdgcn_mfma_f32_16x16x32_bf16(
                        pf[i], vb[jo], oacc[i][jo], 0, 0, 0);
        }
    }

    // ---- epilogue ----
#pragma unroll
    for (int i = 0; i < 2; ++i) {
#pragma unroll
        for (int r = 0; r < 4; ++r) {
            const float inv = 1.f / lst[i][r];
            const int qg = q0 + wave * 32 + i * 16 + g * 4 + r;
            unsigned short* dst = att + ((size_t)b * SS + qg) * DD + h * 64;
#pragma unroll
            for (int jo = 0; jo < 4; ++jo)
                dst[jo * 16 + l15] = f2bf(oacc[i][jo][r] * inv);
        }
    }
}

// ---------------------------------------------------------------------------
// LayerNorm over D=1024; optional bf16 copy. In-place safe.
// ---------------------------------------------------------------------------
__global__ __launch_bounds__(256) void ln_kernel(
    const float* __restrict__ X, const float* __restrict__ g,
    const float* __restrict__ bta, float* __restrict__ Y,
    unsigned short* __restrict__ Yb) {
    const int row = blockIdx.x;
    const float4 xv = ((const float4*)(X + (size_t)row * DD))[threadIdx.x];

    __shared__ float red1[4], red2[4];
    float s = xv.x + xv.y + xv.z + xv.w;
#pragma unroll
    for (int off = 32; off > 0; off >>= 1) s += __shfl_down(s, off);
    const int wave = threadIdx.x >> 6;
    if ((threadIdx.x & 63) == 0) red1[wave] = s;
    __syncthreads();
    const float mu = (red1[0] + red1[1] + red1[2] + red1[3]) * (1.f / DD);

    float dx = xv.x - mu, dy = xv.y - mu, dz = xv.z - mu, dw = xv.w - mu;
    float s2 = dx * dx + dy * dy + dz * dz + dw * dw;
#pragma unroll
    for (int off = 32; off > 0; off >>= 1) s2 += __shfl_down(s2, off);
    if ((threadIdx.x & 63) == 0) red2[wave] = s2;
    __syncthreads();
    const float var = (red2[0] + red2[1] + red2[2] + red2[3]) * (1.f / DD);
    const float rstd = rsqrtf(var + LN_EPS);

    const float4 gv = ((const float4*)g)[threadIdx.x];
    const float4 bv = ((const float4*)bta)[threadIdx.x];
    float4 yv;
    yv.x = dx * rstd * gv.x + bv.x;
    yv.y = dy * rstd * gv.y + bv.y;
    yv.z = dz * rstd * gv.z + bv.z;
    yv.w = dw * rstd * gv.w + bv.w;
    ((float4*)(Y + (size_t)row * DD))[threadIdx.x] = yv;
    if (Yb) {
        ushort4 q;
        q.x = f2bf(yv.x); q.y = f2bf(yv.y);
        q.z = f2bf(yv.z); q.w = f2bf(yv.w);
        ((ushort4*)(Yb + (size_t)row * DD))[threadIdx.x] = q;
    }
}

// ---------------------------------------------------------------------------
// Workspace (byte offsets, peak 144 MB):
//   [0,16M)    Qb bf16   (ph2-3)    -> out1b bf16 (ph5+)
//   [16M,32M)  Kb bf16   (ph2-3)  \
//   [32M,48M)  VTb bf16  (ph2-3)   > hbuf bf16 [16M,80M) (ph6-7)
//   [96M,102M) Wq2T (ph1-2); [102M,118M) xb (ph1-2)
//   [96M,112M) att bf16 (ph3-4);  [96M,128M) out1 fp32 (ph5-7)
//   [118M,120M) WprojT (ph1-4); [128M,136M) W1T; [136M,144M) W2T
// ---------------------------------------------------------------------------
extern "C" void kernel_launch(void* const* d_in, const int* in_sizes, int n_in,
                              void* d_out, int out_size, void* d_ws,
                              size_t ws_size, hipStream_t stream) {
    const float* x     = (const float*)d_in[0];
    const float* Wqkv  = (const float*)d_in[1];
    const float* Wproj = (const float*)d_in[2];
    const float* bproj = (const float*)d_in[3];
    const float* ln1_g = (const float*)d_in[4];
    const float* ln1_b = (const float*)d_in[5];
    const float* ln2_g = (const float*)d_in[6];
    const float* ln2_b = (const float*)d_in[7];
    const float* W1    = (const float*)d_in[8];
    const float* b1    = (const float*)d_in[9];
    const float* W2    = (const float*)d_in[10];
    const float* b2    = (const float*)d_in[11];
    float* out = (float*)d_out;

    const size_t M = (size_t)BB * SS;     // 8192
    const size_t MB = 1024 * 1024;
    char* w = (char*)d_ws;
    unsigned short* Qb     = (unsigned short*)(w + 0);
    unsigned short* out1b  = (unsigned short*)(w + 0);
    unsigned short* Kb     = (unsigned short*)(w + 16 * MB);
    unsigned short* VTb    = (unsigned short*)(w + 32 * MB);
    unsigned short* hbuf   = (unsigned short*)(w + 16 * MB);
    unsigned short* Wq2T   = (unsigned short*)(w + 96 * MB);
    unsigned short* xb     = (unsigned short*)(w + 102 * MB);
    unsigned short* att    = (unsigned short*)(w + 96 * MB);
    float*          out1   = (float*)(w + 96 * MB);
    unsigned short* WprojT = (unsigned short*)(w + 118 * MB);
    unsigned short* W1T    = (unsigned short*)(w + 128 * MB);
    unsigned short* W2T    = (unsigned short*)(w + 136 * MB);

    // 1. weight/input conversions
    repack_wqkv_bf16_kernel<<<dim3(3, 16, 16), 256, 0, stream>>>(Wqkv, Wq2T);
    transpose_bf16_kernel<<<dim3(16, 16), 256, 0, stream>>>(Wproj, WprojT, 1024, 1024);
    transpose_bf16_kernel<<<dim3(64, 16), 256, 0, stream>>>(W1, W1T, 1024, 4096);
    transpose_bf16_kernel<<<dim3(16, 64), 256, 0, stream>>>(W2, W2T, 4096, 1024);
    f2bf_kernel<<<(int)((M * DD + 255) / 256), 256, 0, stream>>>(x, xb, (int)(M * DD));

    // 2. QKV GEMM -> flash layouts Qb/Kb/VTb (bf16)
    mfma_gemm_kernel<4><<<dim3(3072 / 128, M / 128), 256, 0, stream>>>(
        xb, Wq2T, nullptr, nullptr, nullptr, nullptr, Qb, Kb, VTb,
        (int)M, 3072, 1024);

    // 3. flash causal attention -> att bf16
    fattn_kernel<<<dim3(BB * HH, SS / 128), 256, 0, stream>>>(Qb, Kb, VTb, att);

    // 4. proj GEMM + bias + residual(x) -> d_out fp32
    mfma_gemm_kernel<3><<<dim3(1024 / 128, M / 128), 256, 0, stream>>>(
        att, WprojT, out, nullptr, bproj, x, nullptr, nullptr, nullptr,
        (int)M, 1024, 1024);

    // 5. LN1 -> out1 fp32 + out1b bf16
    ln_kernel<<<(int)M, 256, 0, stream>>>(out, ln1_g, ln1_b, out1, out1b);

    // 6. MLP up + GELU -> hbuf bf16
    mfma_gemm_kernel<2><<<dim3(4096 / 128, M / 128), 256, 0, stream>>>(
        out1b, W1T, nullptr, hbuf, b1, nullptr, nullptr, nullptr, nullptr,
        (int)M, 4096, 1024);

    // 7. MLP down + bias + residual(out1) -> d_out fp32
    mfma_gemm_kernel<3><<<dim3(1024 / 128, M / 128), 256, 0, stream>>>(
        hbuf, W2T, out, nullptr, b2, out1, nullptr, nullptr, nullptr,
        (int)M, 1024, 4096);

    // 8. LN2 in-place on d_out
    ln_kernel<<<(int)M, 256, 0, stream>>>(out, ln2_g, ln2_b, out, nullptr);
}

// Round 6
// 615.120 us; speedup vs baseline: 8.1636x; 1.0747x over previous
//
#include <hip/hip_runtime.h>
#include <math.h>

#define BB 4
#define SS 2048
#define DD 1024
#define HH 16
#define DHH 64
#define DFF 4096
static constexpr float LN_EPS = 1e-5f;

typedef __bf16 bf16x8 __attribute__((ext_vector_type(8)));
typedef float f32x4 __attribute__((ext_vector_type(4)));
typedef unsigned short u16x8 __attribute__((ext_vector_type(8)));

__device__ inline unsigned short f2bf(float f) {
    union { float f; unsigned int u; } v; v.f = f;
    unsigned int u = v.u + 0x7FFFu + ((v.u >> 16) & 1u);  // RNE
    return (unsigned short)(u >> 16);
}

// Async global->LDS DMA, 16 B per lane. LDS dest must be wave-uniform base +
// lane*16 (guide §5; learn_hip m97/m104). Drained by the s_waitcnt vmcnt(0)
// the compiler emits before s_barrier.
__device__ __forceinline__ void gl_lds16(const unsigned short* g,
                                         unsigned short* l) {
    __builtin_amdgcn_global_load_lds(
        (const __attribute__((address_space(1))) unsigned int*)g,
        (__attribute__((address_space(3))) unsigned int*)l, 16, 0, 0);
}

// ---------------------------------------------------------------------------
// fp32 [R][C] -> bf16 transposed [C][R]. 64x64 LDS tiles.
// ---------------------------------------------------------------------------
__global__ __launch_bounds__(256) void transpose_bf16_kernel(
    const float* __restrict__ in, unsigned short* __restrict__ outT,
    int R, int C) {
    __shared__ float t[64][65];
    const int r0 = blockIdx.y * 64, c0 = blockIdx.x * 64;
    const int cl = threadIdx.x & 63, rl = threadIdx.x >> 6;
#pragma unroll
    for (int rr = 0; rr < 16; ++rr)
        t[rl + rr * 4][cl] = in[(size_t)(r0 + rl + rr * 4) * C + c0 + cl];
    __syncthreads();
#pragma unroll
    for (int rr = 0; rr < 16; ++rr)
        outT[(size_t)(c0 + rl + rr * 4) * R + r0 + cl] = f2bf(t[cl][rl + rr * 4]);
}

// ---------------------------------------------------------------------------
// Wqkv [H][D][192] fp32 -> Wq2T bf16 [3072][1024] (row n=h*192+e, col k=d).
// ---------------------------------------------------------------------------
__global__ __launch_bounds__(256) void repack_wqkv_bf16_kernel(
    const float* __restrict__ Wqkv, unsigned short* __restrict__ Wq2T) {
    __shared__ float t[64][65];
    const int h = blockIdx.z;
    const int d0 = blockIdx.y * 64, e0 = blockIdx.x * 64;
    const int cl = threadIdx.x & 63, rl = threadIdx.x >> 6;
#pragma unroll
    for (int rr = 0; rr < 16; ++rr)
        t[rl + rr * 4][cl] =
            Wqkv[((size_t)h * DD + d0 + rl + rr * 4) * 192 + e0 + cl];
    __syncthreads();
#pragma unroll
    for (int rr = 0; rr < 16; ++rr)
        Wq2T[((size_t)h * 192 + e0 + rl + rr * 4) * DD + d0 + cl] =
            f2bf(t[cl][rl + rr * 4]);
}

__global__ __launch_bounds__(256) void f2bf_kernel(
    const float* __restrict__ in, unsigned short* __restrict__ out, int n) {
    int i = blockIdx.x * 256 + threadIdx.x;
    if (i < n) out[i] = f2bf(in[i]);
}

// ---------------------------------------------------------------------------
// bf16 MFMA GEMM: C[M,N] = A[M,K] @ BT[N,K]^T. 128x128 tile, 4 waves, BK=32,
// global_load_lds width=16 staging (m97 2-barrier K-loop).
// MODE 2: bf16 out = gelu(C+bias). MODE 3: fp32 out = C+bias+resid.
// MODE 4 (QKV): scatter bf16 into flash layouts Qb[bh][s][64] (x0.125),
//               Kb[bh][s][64], VTb[bh][64][s].
// ---------------------------------------------------------------------------
template <int MODE>
__global__ __launch_bounds__(256) void mfma_gemm_kernel(
    const unsigned short* __restrict__ A, const unsigned short* __restrict__ BT,
    float* __restrict__ Cf, unsigned short* __restrict__ Cb,
    const float* __restrict__ bias, const float* __restrict__ resid,
    unsigned short* __restrict__ Qb, unsigned short* __restrict__ Kb,
    unsigned short* __restrict__ VTb, int M, int N, int K) {
    __shared__ __align__(16) unsigned short Als[128 * 32];
    __shared__ __align__(16) unsigned short Bls[128 * 32];
    const int tid = threadIdx.x;
    const int lane = tid & 63;
    const int wave = tid >> 6;
    const int wr = (wave >> 1) * 64;
    const int wc = (wave & 1) * 64;
    const int row0 = blockIdx.y * 128;
    const int col0 = blockIdx.x * 128;

    const int lr = tid >> 2;          // staging row 0..63 (LDS = base+lane*16)
    const int lk = (tid & 3) * 8;
    const int m_lo = lane & 15;
    const int kq8 = (lane >> 4) * 8;

    f32x4 acc[4][4] = {};

    for (int k0 = 0; k0 < K; k0 += 32) {
        __syncthreads();   // prev iter's LDS frag reads done
        gl_lds16(&A[(size_t)(row0 + lr) * K + k0 + lk], &Als[lr * 32 + lk]);
        gl_lds16(&A[(size_t)(row0 + 64 + lr) * K + k0 + lk],
                 &Als[(64 + lr) * 32 + lk]);
        gl_lds16(&BT[(size_t)(col0 + lr) * K + k0 + lk], &Bls[lr * 32 + lk]);
        gl_lds16(&BT[(size_t)(col0 + 64 + lr) * K + k0 + lk],
                 &Bls[(64 + lr) * 32 + lk]);
        __syncthreads();   // compiler drains vmcnt(0) before barrier

        bf16x8 af[4], bfr[4];
#pragma unroll
        for (int i = 0; i < 4; ++i)
            af[i] = __builtin_bit_cast(
                bf16x8, *(const u16x8*)&Als[(wr + i * 16 + m_lo) * 32 + kq8]);
#pragma unroll
        for (int j = 0; j < 4; ++j)
            bfr[j] = __builtin_bit_cast(
                bf16x8, *(const u16x8*)&Bls[(wc + j * 16 + m_lo) * 32 + kq8]);
#pragma unroll
        for (int i = 0; i < 4; ++i)
#pragma unroll
            for (int j = 0; j < 4; ++j)
                acc[i][j] = __builtin_amdgcn_mfma_f32_16x16x32_bf16(
                    af[i], bfr[j], acc[i][j], 0, 0, 0);
    }

    const int r_base = (lane >> 4) * 4;
    const int c_off = lane & 15;
#pragma unroll
    for (int i = 0; i < 4; ++i) {
#pragma unroll
        for (int j = 0; j < 4; ++j) {
            const int col = col0 + wc + j * 16 + c_off;
            const int rowb = row0 + wr + i * 16 + r_base;
            if (MODE == 4) {
                const int h = col / 192, e = col % 192;
                const int bb = rowb >> 11, s = rowb & 2047;
                if (e < 64) {
                    unsigned short* q =
                        Qb + (((size_t)bb * HH + h) * SS + s) * 64 + e;
#pragma unroll
                    for (int r = 0; r < 4; ++r)
                        q[r * 64] = f2bf(acc[i][j][r] * 0.125f);
                } else if (e < 128) {
                    unsigned short* kp =
                        Kb + (((size_t)bb * HH + h) * SS + s) * 64 + (e - 64);
#pragma unroll
                    for (int r = 0; r < 4; ++r)
                        kp[r * 64] = f2bf(acc[i][j][r]);
                } else {
                    ushort4 pk;
                    pk.x = f2bf(acc[i][j][0]);
                    pk.y = f2bf(acc[i][j][1]);
                    pk.z = f2bf(acc[i][j][2]);
                    pk.w = f2bf(acc[i][j][3]);
                    *(ushort4*)(VTb + (((size_t)bb * HH + h) * 64 + (e - 128)) *
                                          SS + s) = pk;
                }
            } else {
                const float bv = bias[col];
#pragma unroll
                for (int r = 0; r < 4; ++r) {
                    const int row = rowb + r;
                    float v = acc[i][j][r] + bv;
                    if (MODE == 2) {
                        v = 0.5f * v * (1.0f + erff(v * 0.70710678118654752f));
                        Cb[(size_t)row * N + col] = f2bf(v);
                    } else {
                        v += resid[(size_t)row * N + col];
                        Cf[(size_t)row * N + col] = v;
                    }
                }
            }
        }
    }
}

// ---------------------------------------------------------------------------
// Flash causal attention, transposed-score formulation.
// S^T = K Q^T  (A=K tile, B=Q rows)  ->  per-lane col = one q, rows = kv.
// Softmax per q-col: in-register reduce over 16 kv + 2 shuffles (xor16,32).
// O^T = V^T P^T (A=VTls, B=P^T from LDS [q][kv]).
// Block: 128 q of one (b,h); 4 waves x 32 q; kv tiles of 64.
// ---------------------------------------------------------------------------
__global__ __launch_bounds__(256) void fattn_kernel(
    const unsigned short* __restrict__ Qb, const unsigned short* __restrict__ Kb,
    const unsigned short* __restrict__ VTb, unsigned short* __restrict__ att) {
    constexpr int QSTR = 68, KSTR = 68, VSTR = 76, PSTR = 68;
    __shared__ __align__(16) unsigned short Pls[128 * PSTR];   // P^T-as-[q][kv]; Q stage
    __shared__ __align__(16) unsigned short Kls[64 * KSTR];
    __shared__ __align__(16) unsigned short VTls[64 * VSTR];

    const int bh = blockIdx.x;
    const int q0 = blockIdx.y * 128;
    const int tid = threadIdx.x;
    const int lane = tid & 63;
    const int wave = tid >> 6;
    const int l15 = lane & 15;
    const int g = lane >> 4;
    const int b = bh >> 4, h = bh & 15;

    const unsigned short* Qh = Qb + (size_t)bh * SS * 64;
    const unsigned short* Kh = Kb + (size_t)bh * SS * 64;
    const unsigned short* Vh = VTb + (size_t)bh * 64 * SS;

    // ---- stage Q tile (pre-scaled by 0.125) ----
    {
        const int row = tid >> 1, c0 = (tid & 1) * 32;
        const unsigned short* src = Qh + (size_t)(q0 + row) * 64 + c0;
        unsigned short* dst = &Pls[row * QSTR + c0];
#pragma unroll
        for (int c = 0; c < 32; c += 8)
            *(u16x8*)(dst + c) = *(const u16x8*)(src + c);
    }
    __syncthreads();
    bf16x8 qf[2][2];   // B-frag: [n=q=l15][k=dh]
#pragma unroll
    for (int i = 0; i < 2; ++i)
#pragma unroll
        for (int ks = 0; ks < 2; ++ks)
            qf[i][ks] = __builtin_bit_cast(
                bf16x8, *(const u16x8*)&Pls[(wave * 32 + i * 16 + l15) * QSTR +
                                            ks * 32 + g * 8]);
    __syncthreads();   // Q region dead; Pls reused for P^T

    f32x4 oacc[4][2] = {};          // O^T tiles: [jo=dh][i=q]
    float mst[2], lst[2];
#pragma unroll
    for (int i = 0; i < 2; ++i) { mst[i] = -1e30f; lst[i] = 0.f; }

    const int srow = tid >> 2, sc0 = (tid & 3) * 16;
    const int qlim = q0 + wave * 32 + 31;
    const int qrow = wave * 32 + l15;   // + i*16

    for (int t0 = 0; t0 <= q0 + 64; t0 += 64) {
        __syncthreads();  // prev iter frag reads done
        {
            const unsigned short* ksrc = Kh + (size_t)(t0 + srow) * 64 + sc0;
            *(u16x8*)&Kls[srow * KSTR + sc0]     = *(const u16x8*)ksrc;
            *(u16x8*)&Kls[srow * KSTR + sc0 + 8] = *(const u16x8*)(ksrc + 8);
            const unsigned short* vsrc = Vh + (size_t)srow * SS + t0 + sc0;
            *(u16x8*)&VTls[srow * VSTR + sc0]     = *(const u16x8*)vsrc;
            *(u16x8*)&VTls[srow * VSTR + sc0 + 8] = *(const u16x8*)(vsrc + 8);
        }
        __syncthreads();
        if (t0 > qlim) continue;   // fully masked for this wave (uniform)

        // ---- S^T = K Q^T : sacc[j][i], col=q=i*16+l15, row=kv=j*16+g*4+r
        f32x4 sacc[4][2] = {};
#pragma unroll
        for (int ks = 0; ks < 2; ++ks) {
            bf16x8 kb[4];   // A-frag: [m=kv][k=dh]
#pragma unroll
            for (int j = 0; j < 4; ++j)
                kb[j] = __builtin_bit_cast(
                    bf16x8, *(const u16x8*)&Kls[(j * 16 + l15) * KSTR +
                                                ks * 32 + g * 8]);
#pragma unroll
            for (int j = 0; j < 4; ++j)
#pragma unroll
                for (int i = 0; i < 2; ++i)
                    sacc[j][i] = __builtin_amdgcn_mfma_f32_16x16x32_bf16(
                        kb[j], qf[i][ks], sacc[j][i], 0, 0, 0);
        }

        // ---- causal mask ----
        if (t0 >= q0) {
#pragma unroll
            for (int j = 0; j < 4; ++j)
#pragma unroll
                for (int i = 0; i < 2; ++i)
#pragma unroll
                    for (int r = 0; r < 4; ++r) {
                        const int kg = t0 + j * 16 + g * 4 + r;
                        const int qg = q0 + qrow + i * 16;
                        if (kg > qg) sacc[j][i][r] = -1e30f;
                    }
        }

        // ---- online softmax per q-col; P^T -> Pls[q][kv] ----
#pragma unroll
        for (int i = 0; i < 2; ++i) {
            float mx = -1e30f;
#pragma unroll
            for (int j = 0; j < 4; ++j)
#pragma unroll
                for (int r = 0; r < 4; ++r) mx = fmaxf(mx, sacc[j][i][r]);
            mx = fmaxf(mx, __shfl_xor(mx, 16));
            mx = fmaxf(mx, __shfl_xor(mx, 32));
            const float mn = fmaxf(mst[i], mx);
            const float al = __expf(mst[i] - mn);
            mst[i] = mn;
            float rsum = 0.f;
            const int pbase = (qrow + i * 16) * PSTR + g * 4;
#pragma unroll
            for (int j = 0; j < 4; ++j) {
                float p0 = __expf(sacc[j][i][0] - mn);
                float p1 = __expf(sacc[j][i][1] - mn);
                float p2 = __expf(sacc[j][i][2] - mn);
                float p3 = __expf(sacc[j][i][3] - mn);
                rsum += (p0 + p1) + (p2 + p3);
                ushort4 pk;
                pk.x = f2bf(p0); pk.y = f2bf(p1);
                pk.z = f2bf(p2); pk.w = f2bf(p3);
                *(ushort4*)&Pls[pbase + j * 16] = pk;
            }
            rsum += __shfl_xor(rsum, 16);
            rsum += __shfl_xor(rsum, 32);
            lst[i] = lst[i] * al + rsum;
#pragma unroll
            for (int jo = 0; jo < 4; ++jo)
#pragma unroll
                for (int r = 0; r < 4; ++r) oacc[jo][i][r] *= al;
        }
        __syncthreads();   // P^T visible to all lanes of the wave's region
        // (wave-private region; barrier also keeps K/V staging in sync)

        // ---- O^T += V^T P^T ----
#pragma unroll
        for (int ks = 0; ks < 2; ++ks) {
            bf16x8 vb[4], pf[2];
#pragma unroll
            for (int jo = 0; jo < 4; ++jo)
                vb[jo] = __builtin_bit_cast(
                    bf16x8, *(const u16x8*)&VTls[(jo * 16 + l15) * VSTR +
                                                 ks * 32 + g * 8]);
#pragma unroll
            for (int i = 0; i < 2; ++i)
                pf[i] = __builtin_bit_cast(
                    bf16x8, *(const u16x8*)&Pls[(qrow + i * 16) * PSTR +
                                                ks * 32 + g * 8]);
#pragma unroll
            for (int jo = 0; jo < 4; ++jo)
#pragma unroll
                for (int i = 0; i < 2; ++i)
                    oacc[jo][i] = __builtin_amdgcn_mfma_f32_16x16x32_bf16(
                        vb[jo], pf[i], oacc[jo][i], 0, 0, 0);
        }
    }

    // ---- epilogue: O^T/l -> att[b, q, h*64+dh], packed ushort4 ----
#pragma unroll
    for (int i = 0; i < 2; ++i) {
        const float inv = 1.f / lst[i];
        const int qg = q0 + qrow + i * 16;
        unsigned short* dst = att + ((size_t)b * SS + qg) * DD + h * 64 + g * 4;
#pragma unroll
        for (int jo = 0; jo < 4; ++jo) {
            ushort4 pk;
            pk.x = f2bf(oacc[jo][i][0] * inv);
            pk.y = f2bf(oacc[jo][i][1] * inv);
            pk.z = f2bf(oacc[jo][i][2] * inv);
            pk.w = f2bf(oacc[jo][i][3] * inv);
            *(ushort4*)(dst + jo * 16) = pk;
        }
    }
}

// ---------------------------------------------------------------------------
// LayerNorm over D=1024; optional bf16 copy. In-place safe.
// ---------------------------------------------------------------------------
__global__ __launch_bounds__(256) void ln_kernel(
    const float* __restrict__ X, const float* __restrict__ g,
    const float* __restrict__ bta, float* __restrict__ Y,
    unsigned short* __restrict__ Yb) {
    const int row = blockIdx.x;
    const float4 xv = ((const float4*)(X + (size_t)row * DD))[threadIdx.x];

    __shared__ float red1[4], red2[4];
    float s = xv.x + xv.y + xv.z + xv.w;
#pragma unroll
    for (int off = 32; off > 0; off >>= 1) s += __shfl_down(s, off);
    const int wave = threadIdx.x >> 6;
    if ((threadIdx.x & 63) == 0) red1[wave] = s;
    __syncthreads();
    const float mu = (red1[0] + red1[1] + red1[2] + red1[3]) * (1.f / DD);

    float dx = xv.x - mu, dy = xv.y - mu, dz = xv.z - mu, dw = xv.w - mu;
    float s2 = dx * dx + dy * dy + dz * dz + dw * dw;
#pragma unroll
    for (int off = 32; off > 0; off >>= 1) s2 += __shfl_down(s2, off);
    if ((threadIdx.x & 63) == 0) red2[wave] = s2;
    __syncthreads();
    const float var = (red2[0] + red2[1] + red2[2] + red2[3]) * (1.f / DD);
    const float rstd = rsqrtf(var + LN_EPS);

    const float4 gv = ((const float4*)g)[threadIdx.x];
    const float4 bv = ((const float4*)bta)[threadIdx.x];
    float4 yv;
    yv.x = dx * rstd * gv.x + bv.x;
    yv.y = dy * rstd * gv.y + bv.y;
    yv.z = dz * rstd * gv.z + bv.z;
    yv.w = dw * rstd * gv.w + bv.w;
    ((float4*)(Y + (size_t)row * DD))[threadIdx.x] = yv;
    if (Yb) {
        ushort4 q;
        q.x = f2bf(yv.x); q.y = f2bf(yv.y);
        q.z = f2bf(yv.z); q.w = f2bf(yv.w);
        ((ushort4*)(Yb + (size_t)row * DD))[threadIdx.x] = q;
    }
}

// ---------------------------------------------------------------------------
// Workspace (byte offsets, peak 144 MB):
//   [0,16M)    Qb bf16 (ph2-3) -> out1b bf16 (ph5+)
//   [16M,32M)  Kb; [32M,48M) VTb (ph2-3) -> hbuf bf16 [16M,80M) (ph6-7)
//   [96M,102M) Wq2T; [102M,118M) xb (ph1-2)
//   [96M,112M) att bf16 (ph3-4); [96M,128M) out1 fp32 (ph5-7)
//   [118M,120M) WprojT; [128M,136M) W1T; [136M,144M) W2T
// ---------------------------------------------------------------------------
extern "C" void kernel_launch(void* const* d_in, const int* in_sizes, int n_in,
                              void* d_out, int out_size, void* d_ws,
                              size_t ws_size, hipStream_t stream) {
    const float* x     = (const float*)d_in[0];
    const float* Wqkv  = (const float*)d_in[1];
    const float* Wproj = (const float*)d_in[2];
    const float* bproj = (const float*)d_in[3];
    const float* ln1_g = (const float*)d_in[4];
    const float* ln1_b = (const float*)d_in[5];
    const float* ln2_g = (const float*)d_in[6];
    const float* ln2_b = (const float*)d_in[7];
    const float* W1    = (const float*)d_in[8];
    const float* b1    = (const float*)d_in[9];
    const float* W2    = (const float*)d_in[10];
    const float* b2    = (const float*)d_in[11];
    float* out = (float*)d_out;

    const size_t M = (size_t)BB * SS;     // 8192
    const size_t MB = 1024 * 1024;
    char* w = (char*)d_ws;
    unsigned short* Qb     = (unsigned short*)(w + 0);
    unsigned short* out1b  = (unsigned short*)(w + 0);
    unsigned short* Kb     = (unsigned short*)(w + 16 * MB);
    unsigned short* VTb    = (unsigned short*)(w + 32 * MB);
    unsigned short* hbuf   = (unsigned short*)(w + 16 * MB);
    unsigned short* Wq2T   = (unsigned short*)(w + 96 * MB);
    unsigned short* xb     = (unsigned short*)(w + 102 * MB);
    unsigned short* att    = (unsigned short*)(w + 96 * MB);
    float*          out1   = (float*)(w + 96 * MB);
    unsigned short* WprojT = (unsigned short*)(w + 118 * MB);
    unsigned short* W1T    = (unsigned short*)(w + 128 * MB);
    unsigned short* W2T    = (unsigned short*)(w + 136 * MB);

    // 1. weight/input conversions
    repack_wqkv_bf16_kernel<<<dim3(3, 16, 16), 256, 0, stream>>>(Wqkv, Wq2T);
    transpose_bf16_kernel<<<dim3(16, 16), 256, 0, stream>>>(Wproj, WprojT, 1024, 1024);
    transpose_bf16_kernel<<<dim3(64, 16), 256, 0, stream>>>(W1, W1T, 1024, 4096);
    transpose_bf16_kernel<<<dim3(16, 64), 256, 0, stream>>>(W2, W2T, 4096, 1024);
    f2bf_kernel<<<(int)((M * DD + 255) / 256), 256, 0, stream>>>(x, xb, (int)(M * DD));

    // 2. QKV GEMM -> flash layouts Qb/Kb/VTb (bf16)
    mfma_gemm_kernel<4><<<dim3(3072 / 128, M / 128), 256, 0, stream>>>(
        xb, Wq2T, nullptr, nullptr, nullptr, nullptr, Qb, Kb, VTb,
        (int)M, 3072, 1024);

    // 3. flash causal attention -> att bf16
    fattn_kernel<<<dim3(BB * HH, SS / 128), 256, 0, stream>>>(Qb, Kb, VTb, att);

    // 4. proj GEMM + bias + residual(x) -> d_out fp32
    mfma_gemm_kernel<3><<<dim3(1024 / 128, M / 128), 256, 0, stream>>>(
        att, WprojT, out, nullptr, bproj, x, nullptr, nullptr, nullptr,
        (int)M, 1024, 1024);

    // 5. LN1 -> out1 fp32 + out1b bf16
    ln_kernel<<<(int)M, 256, 0, stream>>>(out, ln1_g, ln1_b, out1, out1b);

    // 6. MLP up + GELU -> hbuf bf16
    mfma_gemm_kernel<2><<<dim3(4096 / 128, M / 128), 256, 0, stream>>>(
        out1b, W1T, nullptr, hbuf, b1, nullptr, nullptr, nullptr, nullptr,
        (int)M, 4096, 1024);

    // 7. MLP down + bias + residual(out1) -> d_out fp32
    mfma_gemm_kernel<3><<<dim3(1024 / 128, M / 128), 256, 0, stream>>>(
        hbuf, W2T, out, nullptr, b2, out1, nullptr, nullptr, nullptr,
        (int)M, 1024, 4096);

    // 8. LN2 in-place on d_out
    ln_kernel<<<(int)M, 256, 0, stream>>>(out, ln2_g, ln2_b, out, nullptr);
}

// Round 8
// 585.328 us; speedup vs baseline: 8.5791x; 1.0509x over previous
//
#include <hip/hip_runtime.h>
#include <math.h>

#define BB 4
#define SS 2048
#define DD 1024
#define HH 16
#define DHH 64
#define DFF 4096
static constexpr float LN_EPS = 1e-5f;

typedef __bf16 bf16x8 __attribute__((ext_vector_type(8)));
typedef float f32x4 __attribute__((ext_vector_type(4)));
typedef unsigned short u16x8 __attribute__((ext_vector_type(8)));

__device__ inline unsigned short f2bf(float f) {
    union { float f; unsigned int u; } v; v.f = f;
    unsigned int u = v.u + 0x7FFFu + ((v.u >> 16) & 1u);  // RNE
    return (unsigned short)(u >> 16);
}

// Fast 2^x via the gfx hardware exp2 (v_exp_f32).
__device__ __forceinline__ float fexp2(float x) {
    return __builtin_amdgcn_exp2f(x);
}

// Async global->LDS DMA, 16 B/lane; LDS dest = wave-uniform base + lane*16.
__device__ __forceinline__ void gl_lds16(const unsigned short* g,
                                         unsigned short* l) {
    __builtin_amdgcn_global_load_lds(
        (const __attribute__((address_space(1))) unsigned int*)g,
        (__attribute__((address_space(3))) unsigned int*)l, 16, 0, 0);
}

// ---------------------------------------------------------------------------
// fp32 [R][C] -> bf16 transposed [C][R]. 64x64 LDS tiles.
// ---------------------------------------------------------------------------
__global__ __launch_bounds__(256) void transpose_bf16_kernel(
    const float* __restrict__ in, unsigned short* __restrict__ outT,
    int R, int C) {
    __shared__ float t[64][65];
    const int r0 = blockIdx.y * 64, c0 = blockIdx.x * 64;
    const int cl = threadIdx.x & 63, rl = threadIdx.x >> 6;
#pragma unroll
    for (int rr = 0; rr < 16; ++rr)
        t[rl + rr * 4][cl] = in[(size_t)(r0 + rl + rr * 4) * C + c0 + cl];
    __syncthreads();
#pragma unroll
    for (int rr = 0; rr < 16; ++rr)
        outT[(size_t)(c0 + rl + rr * 4) * R + r0 + cl] = f2bf(t[cl][rl + rr * 4]);
}

// ---------------------------------------------------------------------------
// Wqkv [H][D][192] fp32 -> Wq2T bf16 [3072][1024] (row n=h*192+e, col k=d).
// ---------------------------------------------------------------------------
__global__ __launch_bounds__(256) void repack_wqkv_bf16_kernel(
    const float* __restrict__ Wqkv, unsigned short* __restrict__ Wq2T) {
    __shared__ float t[64][65];
    const int h = blockIdx.z;
    const int d0 = blockIdx.y * 64, e0 = blockIdx.x * 64;
    const int cl = threadIdx.x & 63, rl = threadIdx.x >> 6;
#pragma unroll
    for (int rr = 0; rr < 16; ++rr)
        t[rl + rr * 4][cl] =
            Wqkv[((size_t)h * DD + d0 + rl + rr * 4) * 192 + e0 + cl];
    __syncthreads();
#pragma unroll
    for (int rr = 0; rr < 16; ++rr)
        Wq2T[((size_t)h * 192 + e0 + rl + rr * 4) * DD + d0 + cl] =
            f2bf(t[cl][rl + rr * 4]);
}

__global__ __launch_bounds__(256) void f2bf_kernel(
    const float* __restrict__ in, unsigned short* __restrict__ out, int n) {
    int i = blockIdx.x * 256 + threadIdx.x;
    if (i < n) out[i] = f2bf(in[i]);
}

// ---------------------------------------------------------------------------
// bf16 MFMA GEMM: C[M,N] = A[M,K] @ BT[N,K]^T. 128x128 tile, 4 waves, BK=32,
// global_load_lds 16B staging with XOR-swizzled k-chunks (conflict-free
// ds_read_b128 frag reads: thread tid DMAs global chunk (tid&3)^((lr>>1)&3)
// into LDS slot tid&3; frag reads chunk g from slot g^((l15>>1)&3)).
// MODE 2: bf16 out = gelu_tanh(C+bias), via-LDS repack, u16x8 stores.
// MODE 3: fp32 out = C+bias+resid.
// MODE 4 (QKV): scatter bf16 to Qb[bh][s][64] (x 0.125*log2e),
//               Kb[bh][s][64], VTb[bh][64][s].
// ---------------------------------------------------------------------------
template <int MODE>
__global__ __launch_bounds__(256) void mfma_gemm_kernel(
    const unsigned short* __restrict__ A, const unsigned short* __restrict__ BT,
    float* __restrict__ Cf, unsigned short* __restrict__ Cb,
    const float* __restrict__ bias, const float* __restrict__ resid,
    unsigned short* __restrict__ Qb, unsigned short* __restrict__ Kb,
    unsigned short* __restrict__ VTb, int M, int N, int K) {
    __shared__ __align__(16) unsigned short lds_g[128 * 32 * 2];
    unsigned short* Als = lds_g;            // 128*32
    unsigned short* Bls = lds_g + 128 * 32; // 128*32
    const int tid = threadIdx.x;
    const int lane = tid & 63;
    const int wave = tid >> 6;
    const int wr = (wave >> 1) * 64;
    const int wc = (wave & 1) * 64;
    const int row0 = blockIdx.y * 128;
    const int col0 = blockIdx.x * 128;

    const int lr = tid >> 2;                      // staging row 0..63
    const int lsl = (tid & 3) * 8;                // LDS slot offset (elements)
    const int lkg = (((tid & 3) ^ ((lr >> 1) & 3)) * 8);  // global k-chunk
    const int l15 = lane & 15;
    const int g = lane >> 4;
    const int fk = ((g ^ ((l15 >> 1) & 3)) * 8);  // frag-read slot offset

    f32x4 acc[4][4] = {};

    for (int k0 = 0; k0 < K; k0 += 32) {
        __syncthreads();   // prev iter's LDS frag reads done
        gl_lds16(&A[(size_t)(row0 + lr) * K + k0 + lkg], &Als[lr * 32 + lsl]);
        gl_lds16(&A[(size_t)(row0 + 64 + lr) * K + k0 + lkg],
                 &Als[(64 + lr) * 32 + lsl]);
        gl_lds16(&BT[(size_t)(col0 + lr) * K + k0 + lkg], &Bls[lr * 32 + lsl]);
        gl_lds16(&BT[(size_t)(col0 + 64 + lr) * K + k0 + lkg],
                 &Bls[(64 + lr) * 32 + lsl]);
        __syncthreads();   // vmcnt(0) drain before barrier

        bf16x8 af[4], bfr[4];
#pragma unroll
        for (int i = 0; i < 4; ++i)
            af[i] = __builtin_bit_cast(
                bf16x8, *(const u16x8*)&Als[(wr + i * 16 + l15) * 32 + fk]);
#pragma unroll
        for (int j = 0; j < 4; ++j)
            bfr[j] = __builtin_bit_cast(
                bf16x8, *(const u16x8*)&Bls[(wc + j * 16 + l15) * 32 + fk]);
#pragma unroll
        for (int i = 0; i < 4; ++i)
#pragma unroll
            for (int j = 0; j < 4; ++j)
                acc[i][j] = __builtin_amdgcn_mfma_f32_16x16x32_bf16(
                    af[i], bfr[j], acc[i][j], 0, 0, 0);
    }

    const int r_base = (lane >> 4) * 4;
    const int c_off = l15;

    if (MODE == 2) {
        // via-LDS repack: per i, a 32-row x 128-col bf16 slab (stride 136).
        const int slab = (wave >> 1) * 16 + r_base;
#pragma unroll
        for (int i = 0; i < 4; ++i) {
            __syncthreads();   // prior lds_g reads done
#pragma unroll
            for (int j = 0; j < 4; ++j) {
                const int col = wc + j * 16 + c_off;
                const float bv = bias[col0 + col];
#pragma unroll
                for (int r = 0; r < 4; ++r) {
                    float v = acc[i][j][r] + bv;
                    // gelu_tanh: v * t/(t+1), t = 2^(v*(2.302118+0.102942 v^2))
                    float t = fexp2(v * (2.30211849f + 0.10294198f * v * v));
                    float gel = v * t * __builtin_amdgcn_rcpf(t + 1.f);
                    lds_g[(slab + r) * 136 + col] = f2bf(gel);
                }
            }
            __syncthreads();
#pragma unroll
            for (int it = 0; it < 2; ++it) {
                const int id = it * 256 + tid;
                const int sl = id >> 4, cc = (id & 15) * 8;
                const int row_g = row0 + ((sl < 16) ? (i * 16 + sl)
                                                    : (48 + i * 16 + sl));
                *(u16x8*)&Cb[(size_t)row_g * N + col0 + cc] =
                    *(const u16x8*)&lds_g[sl * 136 + cc];
            }
        }
        return;
    }

#pragma unroll
    for (int i = 0; i < 4; ++i) {
#pragma unroll
        for (int j = 0; j < 4; ++j) {
            const int col = col0 + wc + j * 16 + c_off;
            const int rowb = row0 + wr + i * 16 + r_base;
            if (MODE == 4) {
                const int h = col / 192, e = col % 192;
                const int bb = rowb >> 11, s = rowb & 2047;
                if (e < 64) {
                    unsigned short* q =
                        Qb + (((size_t)bb * HH + h) * SS + s) * 64 + e;
#pragma unroll
                    for (int r = 0; r < 4; ++r)
                        q[r * 64] = f2bf(acc[i][j][r] * 0.18033688f);
                } else if (e < 128) {
                    unsigned short* kp =
                        Kb + (((size_t)bb * HH + h) * SS + s) * 64 + (e - 64);
#pragma unroll
                    for (int r = 0; r < 4; ++r)
                        kp[r * 64] = f2bf(acc[i][j][r]);
                } else {
                    ushort4 pk;
                    pk.x = f2bf(acc[i][j][0]);
                    pk.y = f2bf(acc[i][j][1]);
                    pk.z = f2bf(acc[i][j][2]);
                    pk.w = f2bf(acc[i][j][3]);
                    *(ushort4*)(VTb + (((size_t)bb * HH + h) * 64 + (e - 128)) *
                                          SS + s) = pk;
                }
            } else {
                const float bv = bias[col];
#pragma unroll
                for (int r = 0; r < 4; ++r) {
                    const int row = rowb + r;
                    float v = acc[i][j][r] + bv + resid[(size_t)row * N + col];
                    Cf[(size_t)row * N + col] = v;
                }
            }
        }
    }
}

// ---------------------------------------------------------------------------
// Flash causal attention, transposed-score formulation, exp2 domain
// (Q pre-scaled by 0.125*log2e in the QKV epilogue).
// S^T = K Q^T; softmax per q-col (2 shuffles); O^T = V^T P^T.
// Block: 128 q of one (b,h); 4 waves x 32 q; kv tiles of 64.
// ---------------------------------------------------------------------------
__global__ __launch_bounds__(256) void fattn_kernel(
    const unsigned short* __restrict__ Qb, const unsigned short* __restrict__ Kb,
    const unsigned short* __restrict__ VTb, unsigned short* __restrict__ att) {
    constexpr int QSTR = 68, KSTR = 68, VSTR = 76, PSTR = 68;
    __shared__ __align__(16) unsigned short Pls[128 * PSTR];
    __shared__ __align__(16) unsigned short Kls[64 * KSTR];
    __shared__ __align__(16) unsigned short VTls[64 * VSTR];

    const int bh = blockIdx.x;
    const int q0 = blockIdx.y * 128;
    const int tid = threadIdx.x;
    const int lane = tid & 63;
    const int wave = tid >> 6;
    const int l15 = lane & 15;
    const int g = lane >> 4;
    const int b = bh >> 4, h = bh & 15;

    const unsigned short* Qh = Qb + (size_t)bh * SS * 64;
    const unsigned short* Kh = Kb + (size_t)bh * SS * 64;
    const unsigned short* Vh = VTb + (size_t)bh * 64 * SS;

    // ---- stage Q tile ----
    {
        const int row = tid >> 1, c0 = (tid & 1) * 32;
        const unsigned short* src = Qh + (size_t)(q0 + row) * 64 + c0;
        unsigned short* dst = &Pls[row * QSTR + c0];
#pragma unroll
        for (int c = 0; c < 32; c += 8)
            *(u16x8*)(dst + c) = *(const u16x8*)(src + c);
    }
    __syncthreads();
    bf16x8 qf[2][2];   // B-frag: [n=q=l15][k=dh]
#pragma unroll
    for (int i = 0; i < 2; ++i)
#pragma unroll
        for (int ks = 0; ks < 2; ++ks)
            qf[i][ks] = __builtin_bit_cast(
                bf16x8, *(const u16x8*)&Pls[(wave * 32 + i * 16 + l15) * QSTR +
                                            ks * 32 + g * 8]);
    __syncthreads();   // Q region dead; Pls reused for P^T

    f32x4 oacc[4][2] = {};          // O^T tiles: [jo=dh][i=q]
    float mst[2], lst[2];
#pragma unroll
    for (int i = 0; i < 2; ++i) { mst[i] = -1e30f; lst[i] = 0.f; }

    const int srow = tid >> 2, sc0 = (tid & 3) * 16;
    const int qlim = q0 + wave * 32 + 31;
    const int qrow = wave * 32 + l15;

    for (int t0 = 0; t0 <= q0 + 64; t0 += 64) {
        __syncthreads();
        {
            const unsigned short* ksrc = Kh + (size_t)(t0 + srow) * 64 + sc0;
            *(u16x8*)&Kls[srow * KSTR + sc0]     = *(const u16x8*)ksrc;
            *(u16x8*)&Kls[srow * KSTR + sc0 + 8] = *(const u16x8*)(ksrc + 8);
            const unsigned short* vsrc = Vh + (size_t)srow * SS + t0 + sc0;
            *(u16x8*)&VTls[srow * VSTR + sc0]     = *(const u16x8*)vsrc;
            *(u16x8*)&VTls[srow * VSTR + sc0 + 8] = *(const u16x8*)(vsrc + 8);
        }
        __syncthreads();
        if (t0 > qlim) continue;

        // ---- S^T = K Q^T ----
        f32x4 sacc[4][2] = {};
#pragma unroll
        for (int ks = 0; ks < 2; ++ks) {
            bf16x8 kb[4];
#pragma unroll
            for (int j = 0; j < 4; ++j)
                kb[j] = __builtin_bit_cast(
                    bf16x8, *(const u16x8*)&Kls[(j * 16 + l15) * KSTR +
                                                ks * 32 + g * 8]);
#pragma unroll
            for (int j = 0; j < 4; ++j)
#pragma unroll
                for (int i = 0; i < 2; ++i)
                    sacc[j][i] = __builtin_amdgcn_mfma_f32_16x16x32_bf16(
                        kb[j], qf[i][ks], sacc[j][i], 0, 0, 0);
        }

        // ---- causal mask ----
        if (t0 >= q0) {
#pragma unroll
            for (int j = 0; j < 4; ++j)
#pragma unroll
                for (int i = 0; i < 2; ++i)
#pragma unroll
                    for (int r = 0; r < 4; ++r) {
                        const int kg = t0 + j * 16 + g * 4 + r;
                        const int qg = q0 + qrow + i * 16;
                        if (kg > qg) sacc[j][i][r] = -1e30f;
                    }
        }

        // ---- online softmax (exp2 domain); P^T -> Pls[q][kv] ----
#pragma unroll
        for (int i = 0; i < 2; ++i) {
            float mx = -1e30f;
#pragma unroll
            for (int j = 0; j < 4; ++j)
#pragma unroll
                for (int r = 0; r < 4; ++r) mx = fmaxf(mx, sacc[j][i][r]);
            mx = fmaxf(mx, __shfl_xor(mx, 16));
            mx = fmaxf(mx, __shfl_xor(mx, 32));
            const float mn = fmaxf(mst[i], mx);
            const float al = fexp2(mst[i] - mn);
            mst[i] = mn;
            float rsum = 0.f;
            const int pbase = (qrow + i * 16) * PSTR + g * 4;
#pragma unroll
            for (int j = 0; j < 4; ++j) {
                float p0 = fexp2(sacc[j][i][0] - mn);
                float p1 = fexp2(sacc[j][i][1] - mn);
                float p2 = fexp2(sacc[j][i][2] - mn);
                float p3 = fexp2(sacc[j][i][3] - mn);
                rsum += (p0 + p1) + (p2 + p3);
                ushort4 pk;
                pk.x = f2bf(p0); pk.y = f2bf(p1);
                pk.z = f2bf(p2); pk.w = f2bf(p3);
                *(ushort4*)&Pls[pbase + j * 16] = pk;
            }
            rsum += __shfl_xor(rsum, 16);
            rsum += __shfl_xor(rsum, 32);
            lst[i] = lst[i] * al + rsum;
#pragma unroll
            for (int jo = 0; jo < 4; ++jo)
#pragma unroll
                for (int r = 0; r < 4; ++r) oacc[jo][i][r] *= al;
        }
        __syncthreads();

        // ---- O^T += V^T P^T ----
#pragma unroll
        for (int ks = 0; ks < 2; ++ks) {
            bf16x8 vb[4], pf[2];
#pragma unroll
            for (int jo = 0; jo < 4; ++jo)
                vb[jo] = __builtin_bit_cast(
                    bf16x8, *(const u16x8*)&VTls[(jo * 16 + l15) * VSTR +
                                                 ks * 32 + g * 8]);
#pragma unroll
            for (int i = 0; i < 2; ++i)
                pf[i] = __builtin_bit_cast(
                    bf16x8, *(const u16x8*)&Pls[(qrow + i * 16) * PSTR +
                                                ks * 32 + g * 8]);
#pragma unroll
            for (int jo = 0; jo < 4; ++jo)
#pragma unroll
                for (int i = 0; i < 2; ++i)
                    oacc[jo][i] = __builtin_amdgcn_mfma_f32_16x16x32_bf16(
                        vb[jo], pf[i], oacc[jo][i], 0, 0, 0);
        }
    }

    // ---- epilogue: O^T/l -> att[b, q, h*64+dh], packed ushort4 ----
#pragma unroll
    for (int i = 0; i < 2; ++i) {
        const float inv = 1.f / lst[i];
        const int qg = q0 + qrow + i * 16;
        unsigned short* dst = att + ((size_t)b * SS + qg) * DD + h * 64 + g * 4;
#pragma unroll
        for (int jo = 0; jo < 4; ++jo) {
            ushort4 pk;
            pk.x = f2bf(oacc[jo][i][0] * inv);
            pk.y = f2bf(oacc[jo][i][1] * inv);
            pk.z = f2bf(oacc[jo][i][2] * inv);
            pk.w = f2bf(oacc[jo][i][3] * inv);
            *(ushort4*)(dst + jo * 16) = pk;
        }
    }
}

// ---------------------------------------------------------------------------
// LayerNorm over D=1024; optional bf16 copy. In-place safe.
// ---------------------------------------------------------------------------
__global__ __launch_bounds__(256) void ln_kernel(
    const float* __restrict__ X, const float* __restrict__ g,
    const float* __restrict__ bta, float* __restrict__ Y,
    unsigned short* __restrict__ Yb) {
    const int row = blockIdx.x;
    const float4 xv = ((const float4*)(X + (size_t)row * DD))[threadIdx.x];

    __shared__ float red1[4], red2[4];
    float s = xv.x + xv.y + xv.z + xv.w;
#pragma unroll
    for (int off = 32; off > 0; off >>= 1) s += __shfl_down(s, off);
    const int wave = threadIdx.x >> 6;
    if ((threadIdx.x & 63) == 0) red1[wave] = s;
    __syncthreads();
    const float mu = (red1[0] + red1[1] + red1[2] + red1[3]) * (1.f / DD);

    float dx = xv.x - mu, dy = xv.y - mu, dz = xv.z - mu, dw = xv.w - mu;
    float s2 = dx * dx + dy * dy + dz * dz + dw * dw;
#pragma unroll
    for (int off = 32; off > 0; off >>= 1) s2 += __shfl_down(s2, off);
    if ((threadIdx.x & 63) == 0) red2[wave] = s2;
    __syncthreads();
    const float var = (red2[0] + red2[1] + red2[2] + red2[3]) * (1.f / DD);
    const float rstd = rsqrtf(var + LN_EPS);

    const float4 gv = ((const float4*)g)[threadIdx.x];
    const float4 bv = ((const float4*)bta)[threadIdx.x];
    float4 yv;
    yv.x = dx * rstd * gv.x + bv.x;
    yv.y = dy * rstd * gv.y + bv.y;
    yv.z = dz * rstd * gv.z + bv.z;
    yv.w = dw * rstd * gv.w + bv.w;
    ((float4*)(Y + (size_t)row * DD))[threadIdx.x] = yv;
    if (Yb) {
        ushort4 q;
        q.x = f2bf(yv.x); q.y = f2bf(yv.y);
        q.z = f2bf(yv.z); q.w = f2bf(yv.w);
        ((ushort4*)(Yb + (size_t)row * DD))[threadIdx.x] = q;
    }
}

// ---------------------------------------------------------------------------
// Workspace (byte offsets, peak 144 MB):
//   [0,16M)    Qb bf16 (ph2-3) -> out1b bf16 (ph5+)
//   [16M,32M)  Kb; [32M,48M) VTb (ph2-3) -> hbuf bf16 [16M,80M) (ph6-7)
//   [96M,102M) Wq2T; [102M,118M) xb (ph1-2)
//   [96M,112M) att bf16 (ph3-4); [96M,128M) out1 fp32 (ph5-7)
//   [118M,120M) WprojT; [128M,136M) W1T; [136M,144M) W2T
// ---------------------------------------------------------------------------
extern "C" void kernel_launch(void* const* d_in, const int* in_sizes, int n_in,
                              void* d_out, int out_size, void* d_ws,
                              size_t ws_size, hipStream_t stream) {
    const float* x     = (const float*)d_in[0];
    const float* Wqkv  = (const float*)d_in[1];
    const float* Wproj = (const float*)d_in[2];
    const float* bproj = (const float*)d_in[3];
    const float* ln1_g = (const float*)d_in[4];
    const float* ln1_b = (const float*)d_in[5];
    const float* ln2_g = (const float*)d_in[6];
    const float* ln2_b = (const float*)d_in[7];
    const float* W1    = (const float*)d_in[8];
    const float* b1    = (const float*)d_in[9];
    const float* W2    = (const float*)d_in[10];
    const float* b2    = (const float*)d_in[11];
    float* out = (float*)d_out;

    const size_t M = (size_t)BB * SS;     // 8192
    const size_t MB = 1024 * 1024;
    char* w = (char*)d_ws;
    unsigned short* Qb     = (unsigned short*)(w + 0);
    unsigned short* out1b  = (unsigned short*)(w + 0);
    unsigned short* Kb     = (unsigned short*)(w + 16 * MB);
    unsigned short* VTb    = (unsigned short*)(w + 32 * MB);
    unsigned short* hbuf   = (unsigned short*)(w + 16 * MB);
    unsigned short* Wq2T   = (unsigned short*)(w + 96 * MB);
    unsigned short* xb     = (unsigned short*)(w + 102 * MB);
    unsigned short* att    = (unsigned short*)(w + 96 * MB);
    float*          out1   = (float*)(w + 96 * MB);
    unsigned short* WprojT = (unsigned short*)(w + 118 * MB);
    unsigned short* W1T    = (unsigned short*)(w + 128 * MB);
    unsigned short* W2T    = (unsigned short*)(w + 136 * MB);

    // 1. weight/input conversions
    repack_wqkv_bf16_kernel<<<dim3(3, 16, 16), 256, 0, stream>>>(Wqkv, Wq2T);
    transpose_bf16_kernel<<<dim3(16, 16), 256, 0, stream>>>(Wproj, WprojT, 1024, 1024);
    transpose_bf16_kernel<<<dim3(64, 16), 256, 0, stream>>>(W1, W1T, 1024, 4096);
    transpose_bf16_kernel<<<dim3(16, 64), 256, 0, stream>>>(W2, W2T, 4096, 1024);
    f2bf_kernel<<<(int)((M * DD + 255) / 256), 256, 0, stream>>>(x, xb, (int)(M * DD));

    // 2. QKV GEMM -> flash layouts Qb/Kb/VTb (bf16, Q in exp2 domain)
    mfma_gemm_kernel<4><<<dim3(3072 / 128, M / 128), 256, 0, stream>>>(
        xb, Wq2T, nullptr, nullptr, nullptr, nullptr, Qb, Kb, VTb,
        (int)M, 3072, 1024);

    // 3. flash causal attention -> att bf16
    fattn_kernel<<<dim3(BB * HH, SS / 128), 256, 0, stream>>>(Qb, Kb, VTb, att);

    // 4. proj GEMM + bias + residual(x) -> d_out fp32
    mfma_gemm_kernel<3><<<dim3(1024 / 128, M / 128), 256, 0, stream>>>(
        att, WprojT, out, nullptr, bproj, x, nullptr, nullptr, nullptr,
        (int)M, 1024, 1024);

    // 5. LN1 -> out1 fp32 + out1b bf16
    ln_kernel<<<(int)M, 256, 0, stream>>>(out, ln1_g, ln1_b, out1, out1b);

    // 6. MLP up + GELU -> hbuf bf16
    mfma_gemm_kernel<2><<<dim3(4096 / 128, M / 128), 256, 0, stream>>>(
        out1b, W1T, nullptr, hbuf, b1, nullptr, nullptr, nullptr, nullptr,
        (int)M, 4096, 1024);

    // 7. MLP down + bias + residual(out1) -> d_out fp32
    mfma_gemm_kernel<3><<<dim3(1024 / 128, M / 128), 256, 0, stream>>>(
        hbuf, W2T, out, nullptr, b2, out1, nullptr, nullptr, nullptr,
        (int)M, 1024, 4096);

    // 8. LN2 in-place on d_out
    ln_kernel<<<(int)M, 256, 0, stream>>>(out, ln2_g, ln2_b, out, nullptr);
}